// Round 3
// baseline (251.995 us; speedup 1.0000x reference)
//
#include <hip/hip_runtime.h>

#define SEQ 2048
#define DM 1024
#define NH 16
#define DKH 64
// M rows total = 4*2048 = 8192

typedef __attribute__((ext_vector_type(8))) short short8;   // 8 bf16
typedef __attribute__((ext_vector_type(4))) float f32x4;
typedef __attribute__((ext_vector_type(16))) float f32x16;
typedef __attribute__((ext_vector_type(2))) unsigned int u32x2;
typedef __attribute__((ext_vector_type(4))) unsigned int u32x4;

static __device__ __forceinline__ unsigned short f2b(float f) {
  unsigned int u = __float_as_uint(f);
  u += 0x7fffu + ((u >> 16) & 1u);   // round-to-nearest-even
  return (unsigned short)(u >> 16);
}

static __device__ __forceinline__ short8 ldfrag_bf(const unsigned short* p) {
  return *reinterpret_cast<const short8*>(p);
}
static __device__ __forceinline__ short8 ldfrag_f32(const float* p) {
  const float4* q = reinterpret_cast<const float4*>(p);
  float4 a = q[0], b = q[1];
  short8 r;
  r[0] = (short)f2b(a.x); r[1] = (short)f2b(a.y);
  r[2] = (short)f2b(a.z); r[3] = (short)f2b(a.w);
  r[4] = (short)f2b(b.x); r[5] = (short)f2b(b.y);
  r[6] = (short)f2b(b.z); r[7] = (short)f2b(b.w);
  return r;
}

// async global->LDS, 16 B per lane. LDS side MUST be wave-uniform base + lane*16.
static __device__ __forceinline__ void gl_lds16(const void* g, void* l) {
  __builtin_amdgcn_global_load_lds(
      (const __attribute__((address_space(1))) unsigned int*)g,
      (__attribute__((address_space(3))) unsigned int*)l, 16, 0, 0);
}

__global__ __launch_bounds__(256) void zero_f32(float* __restrict__ p, int n4) {
  int i = blockIdx.x * 256 + threadIdx.x;
  if (i < n4) {
    float4 z = {0.f, 0.f, 0.f, 0.f};
    reinterpret_cast<float4*>(p)[i] = z;
  }
}

// fused cast: blocks [0,8192) cast x (2M float4s); blocks [8192,12288) cast the
// 4 weight matrices (1024 blocks each). wq pre-scaled by 0.125 (exact pow-2).
__global__ __launch_bounds__(256) void cast_all(const float* __restrict__ x,
                                                const float* __restrict__ a, const float* __restrict__ b,
                                                const float* __restrict__ c, const float* __restrict__ d,
                                                unsigned short* __restrict__ xo,
                                                unsigned short* __restrict__ oa, unsigned short* __restrict__ ob,
                                                unsigned short* __restrict__ oc, unsigned short* __restrict__ od) {
  int blk = blockIdx.x;
  if (blk < 8192) {
    int i = blk * 256 + threadIdx.x;
    float4 v = reinterpret_cast<const float4*>(x)[i];
    ushort4 o;
    o.x = f2b(v.x); o.y = f2b(v.y); o.z = f2b(v.z); o.w = f2b(v.w);
    reinterpret_cast<ushort4*>(xo)[i] = o;
  } else {
    blk -= 8192;
    int which = blk >> 10;
    int i = (blk & 1023) * 256 + threadIdx.x;   // [0, 262144) float4s
    const float* s = (which == 0) ? a : (which == 1) ? b : (which == 2) ? c : d;
    unsigned short* o = (which == 0) ? oa : (which == 1) ? ob : (which == 2) ? oc : od;
    float sc = (which == 0) ? 0.125f : 1.0f;
    float4 v = reinterpret_cast<const float4*>(s)[i];
    ushort4 u;
    u.x = f2b(v.x * sc); u.y = f2b(v.y * sc); u.z = f2b(v.z * sc); u.w = f2b(v.w * sc);
    reinterpret_cast<ushort4*>(o)[i] = u;
  }
}

// ---------------- fused QKV GEMM: 128x128 tiles, BK=32, LDS double-buffered --
// Identity block mapping (round-robin XCD spread measured BETTER for FETCH than
// mode-grouped swizzle: 77 vs 127 MB). Epilogue addresses fully hoisted: b and
// h are wave-constant (tiles never cross batch boundary; nw aligns to head),
// so every store offset is a compile-time immediate from one base pointer.
__global__ __launch_bounds__(256) void gemm_qkv(const unsigned short* __restrict__ A,
                                                const unsigned short* __restrict__ Wq,
                                                const unsigned short* __restrict__ Wk,
                                                const unsigned short* __restrict__ Wv,
                                                unsigned short* __restrict__ Qb,
                                                unsigned short* __restrict__ Kb,
                                                unsigned short* __restrict__ Vt) {
  __shared__ char smem[32768];
  unsigned short* At = (unsigned short*)smem;             // 2 bufs x 8 KB
  unsigned short* Wt = (unsigned short*)(smem + 16384);   // 2 bufs x 8 KB
  int t = threadIdx.x;
  int lane = t & 63;
  int w = t >> 6;
  int l16 = lane & 15, q4 = lane >> 4;
  int mode = blockIdx.x % 3;
  int bid = blockIdx.x / 3;
  int mt = bid >> 3, nt = bid & 7;
  int m0 = mt * 128, n0 = nt * 128;
  int mw = (w & 1) * 64, nw = (w >> 1) * 64;
  const unsigned short* W = (mode == 0) ? Wq : (mode == 1) ? Wk : Wv;

  const f32x4 zero4 = {0.f, 0.f, 0.f, 0.f};
  f32x4 acc[4][4];
#pragma unroll
  for (int mi = 0; mi < 4; ++mi)
#pragma unroll
    for (int nj = 0; nj < 4; ++nj) acc[mi][nj] = zero4;

  // staging pointers (advance by 32 ushorts per K-step); source pre-swizzle
  // must be the same involution as the read-side chunk swizzle.
  int rl0 = t >> 2, cp = t & 3;
  int rl1 = rl0 + 64;
  int sw0 = ((cp - rl0 - (rl0 >> 2)) & 3) * 8;
  int sw1 = ((cp - rl1 - (rl1 >> 2)) & 3) * 8;
  const unsigned short* ga0 = A + (long)(m0 + rl0) * DM + sw0;
  const unsigned short* ga1 = A + (long)(m0 + rl1) * DM + sw1;
  const unsigned short* gw0 = W + (long)(n0 + rl0) * DM + sw0;
  const unsigned short* gw1 = W + (long)(n0 + rl1) * DM + sw1;
  char* lA = (char*)At + t * 16;
  char* lW = (char*)Wt + t * 16;

  // hoisted fragment LDS offsets (loop-invariant)
  int aoff[4], woff[4];
#pragma unroll
  for (int mi = 0; mi < 4; ++mi) {
    int r = mw + mi * 16 + l16;
    aoff[mi] = r * 32 + ((q4 + r + (r >> 2)) & 3) * 8;
  }
#pragma unroll
  for (int nj = 0; nj < 4; ++nj) {
    int r = nw + nj * 16 + l16;
    woff[nj] = r * 32 + ((q4 + r + (r >> 2)) & 3) * 8;
  }

  gl_lds16(ga0, lA); gl_lds16(ga1, lA + 4096);
  gl_lds16(gw0, lW); gl_lds16(gw1, lW + 4096);

  for (int ks = 0; ks < 32; ++ks) {
    __syncthreads();                       // tile ks staged + other buf free
    if (ks + 1 < 32) {
      ga0 += 32; ga1 += 32; gw0 += 32; gw1 += 32;
      int bo = ((ks + 1) & 1) * 8192;
      gl_lds16(ga0, lA + bo); gl_lds16(ga1, lA + bo + 4096);
      gl_lds16(gw0, lW + bo); gl_lds16(gw1, lW + bo + 4096);
    }
    const unsigned short* Ab = At + (ks & 1) * 4096;
    const unsigned short* Wb = Wt + (ks & 1) * 4096;

    short8 af[4], wf[4];
#pragma unroll
    for (int mi = 0; mi < 4; ++mi) af[mi] = ldfrag_bf(Ab + aoff[mi]);
#pragma unroll
    for (int nj = 0; nj < 4; ++nj) wf[nj] = ldfrag_bf(Wb + woff[nj]);
#pragma unroll
    for (int mi = 0; mi < 4; ++mi)
#pragma unroll
      for (int nj = 0; nj < 4; ++nj)
        acc[mi][nj] = __builtin_amdgcn_mfma_f32_16x16x32_bf16(af[mi], wf[nj], acc[mi][nj], 0, 0, 0);
  }

  if (mode != 2) {
    // Q/K: [B,H,S,dk]. b,h wave-constant -> single base + immediate offsets.
    unsigned short* o = (mode == 0) ? Qb : Kb;
    int b = m0 >> 11;
    int h = (n0 + nw) >> 6;
    long bh0 = (long)(b * NH + h);
    unsigned short* op = o + (bh0 * SEQ + (m0 & 2047) + mw + q4 * 4) * DKH + l16;
#pragma unroll
    for (int mi = 0; mi < 4; ++mi)
#pragma unroll
      for (int nj = 0; nj < 4; ++nj)
#pragma unroll
        for (int r = 0; r < 4; ++r)
          op[mi * 1024 + r * 64 + nj * 16] = f2b(acc[mi][nj][r]);
  } else {
    // V^T via LDS: wave tile = 64 s-rows x 64 d-cols (exactly one head)
    __syncthreads();                       // everyone done reading K-loop LDS
    unsigned short* vle = (unsigned short*)(smem + w * 8192);   // 64x64 ushorts
    unsigned int* vle32 = (unsigned int*)vle;
#pragma unroll
    for (int nj = 0; nj < 4; ++nj) {
      int d = nj * 16 + l16;
      int k8 = (d & 7) * 8;
#pragma unroll
      for (int mi = 0; mi < 4; ++mi)
#pragma unroll
        for (int r = 0; r < 4; r += 2) {
          int s = mi * 16 + q4 * 4 + r;
          unsigned int pk = (unsigned int)f2b(acc[mi][nj][r]) |
                            ((unsigned int)f2b(acc[mi][nj][r + 1]) << 16);
          vle32[d * 32 + ((s ^ k8) >> 1)] = pk;   // XOR chunk swizzle
        }
    }
    __asm__ volatile("s_waitcnt lgkmcnt(0)" ::: "memory");  // wave-local round-trip
    int b = m0 >> 11;
    int h = (n0 + nw) >> 6;
    long bh = (long)(b * NH + h);
    int sbase = (m0 + mw) & 2047;          // within-batch seq index
    int dr_lo = lane >> 3, c = lane & 7;
    // (dr & 7) == dr_lo for every pass -> read offset is pass-invariant + imm
    const unsigned short* vr = vle + dr_lo * 64 + (c ^ dr_lo) * 8;
    unsigned short* vtp = Vt + (bh * DKH + dr_lo) * SEQ + sbase + c * 8;
#pragma unroll
    for (int pass = 0; pass < 8; ++pass) {
      short8 vv = ldfrag_bf(vr + pass * 512);
      *reinterpret_cast<short8*>(vtp + (long)pass * 8 * SEQ) = vv;
    }
  }
}

// ---------------- O-projection GEMM, double-buffered, ptr-increment ----------
__global__ __launch_bounds__(256) void gemm_o(const unsigned short* __restrict__ A,
                                              const unsigned short* __restrict__ W,
                                              float* __restrict__ outp) {
  __shared__ char smem[32768];
  unsigned short* At = (unsigned short*)smem;
  unsigned short* Wt = (unsigned short*)(smem + 16384);
  int t = threadIdx.x;
  int lane = t & 63;
  int w = t >> 6;
  int l16 = lane & 15, q4 = lane >> 4;
  // bijective XCD swizzle: 512 blocks = 8 XCDs x 64
  int swz = (blockIdx.x & 7) * 64 + (blockIdx.x >> 3);
  int mt = swz >> 3, nt = swz & 7;
  int m0 = mt * 128, n0 = nt * 128;
  int mw = (w & 1) * 64, nw = (w >> 1) * 64;

  const f32x4 zero4 = {0.f, 0.f, 0.f, 0.f};
  f32x4 acc[4][4];
#pragma unroll
  for (int mi = 0; mi < 4; ++mi)
#pragma unroll
    for (int nj = 0; nj < 4; ++nj) acc[mi][nj] = zero4;

  int rl0 = t >> 2, cp = t & 3;
  int rl1 = rl0 + 64;
  int sw0 = ((cp - rl0 - (rl0 >> 2)) & 3) * 8;
  int sw1 = ((cp - rl1 - (rl1 >> 2)) & 3) * 8;
  // A is [B,H,S,dk] head-chunked: k advances 32 within a head, then hops heads
  int b0 = m0 >> 11;
  const unsigned short* ga0;
  const unsigned short* ga1;
  {
    int s0 = (m0 & 2047) + rl0;
    ga0 = A + (long)b0 * (NH * SEQ * DKH) + (long)s0 * DKH + sw0;
    int s1 = (m0 & 2047) + rl1;
    ga1 = A + (long)b0 * (NH * SEQ * DKH) + (long)s1 * DKH + sw1;
  }
  const unsigned short* gw0 = W + (long)(n0 + rl0) * DM + sw0;
  const unsigned short* gw1 = W + (long)(n0 + rl1) * DM + sw1;
  char* lA = (char*)At + t * 16;
  char* lW = (char*)Wt + t * 16;

  int aoff[4], woff[4];
#pragma unroll
  for (int mi = 0; mi < 4; ++mi) {
    int r = mw + mi * 16 + l16;
    aoff[mi] = r * 32 + ((q4 + r + (r >> 2)) & 3) * 8;
  }
#pragma unroll
  for (int nj = 0; nj < 4; ++nj) {
    int r = nw + nj * 16 + l16;
    woff[nj] = r * 32 + ((q4 + r + (r >> 2)) & 3) * 8;
  }

  gl_lds16(ga0, lA); gl_lds16(ga1, lA + 4096);
  gl_lds16(gw0, lW); gl_lds16(gw1, lW + 4096);

  for (int ks = 0; ks < 32; ++ks) {
    __syncthreads();
    if (ks + 1 < 32) {
      int adv = ((ks & 1) == 0) ? 32 : (SEQ * DKH - 32);   // head-hop on odd ks
      ga0 += adv; ga1 += adv; gw0 += 32; gw1 += 32;
      int bo = ((ks + 1) & 1) * 8192;
      gl_lds16(ga0, lA + bo); gl_lds16(ga1, lA + bo + 4096);
      gl_lds16(gw0, lW + bo); gl_lds16(gw1, lW + bo + 4096);
    }
    const unsigned short* Ab = At + (ks & 1) * 4096;
    const unsigned short* Wb = Wt + (ks & 1) * 4096;

    short8 af[4], wf[4];
#pragma unroll
    for (int mi = 0; mi < 4; ++mi) af[mi] = ldfrag_bf(Ab + aoff[mi]);
#pragma unroll
    for (int nj = 0; nj < 4; ++nj) wf[nj] = ldfrag_bf(Wb + woff[nj]);
#pragma unroll
    for (int mi = 0; mi < 4; ++mi)
#pragma unroll
      for (int nj = 0; nj < 4; ++nj)
        acc[mi][nj] = __builtin_amdgcn_mfma_f32_16x16x32_bf16(af[mi], wf[nj], acc[mi][nj], 0, 0, 0);
  }

  // hoisted epilogue: one base, compile-time offsets
  {
    float* op = outp + (long)(m0 + mw + q4 * 4) * DM + n0 + nw + l16;
#pragma unroll
    for (int mi = 0; mi < 4; ++mi)
#pragma unroll
      for (int nj = 0; nj < 4; ++nj)
#pragma unroll
        for (int r = 0; r < 4; ++r)
          op[(mi * 16 + r) * DM + nj * 16] = acc[mi][nj][r];
  }
}

// ---------------- slow GEMM (direct-global, fp32 cvt) — small-ws fallback ----
template<int MODE, bool AF32, bool WF32>
__global__ __launch_bounds__(256) void gemm_s(const void* __restrict__ Ap,
                                              const void* __restrict__ Wp,
                                              void* __restrict__ outp) {
  int wid  = (blockIdx.x * 256 + threadIdx.x) >> 6;
  int lane = threadIdx.x & 63;
  int l16  = lane & 15, q4 = lane >> 4;
  int tn = wid & 15, tm = wid >> 4;
  int m0 = tm * 32, n0 = tn * 64;

  const float*          Af = (const float*)Ap;
  const unsigned short* Ab = (const unsigned short*)Ap;
  const float*          Wf = (const float*)Wp;
  const unsigned short* Wb = (const unsigned short*)Wp;

  const f32x4 zero4 = {0.f, 0.f, 0.f, 0.f};
  f32x4 acc[2][4];
#pragma unroll
  for (int mi = 0; mi < 2; ++mi)
#pragma unroll
    for (int j = 0; j < 4; ++j) acc[mi][j] = zero4;

  int wrow[4];
#pragma unroll
  for (int j = 0; j < 4; ++j) wrow[j] = (n0 + j * 16 + l16) * DM;
  int arow[2] = {0, 0};
  long abase[2] = {0, 0};
  if (MODE != 3) {
#pragma unroll
    for (int mi = 0; mi < 2; ++mi) arow[mi] = (m0 + mi * 16 + l16) * DM;
  } else {
    int b = m0 >> 11;
#pragma unroll
    for (int mi = 0; mi < 2; ++mi) {
      int srow = (m0 & 2047) + mi * 16 + l16;
      abase[mi] = (long)b * (NH * SEQ * DKH) + (long)srow * DKH;
    }
  }

#pragma unroll 2
  for (int ks = 0; ks < 32; ++ks) {
    int ko = ks * 32 + q4 * 8;
    short8 bfrag[4];
#pragma unroll
    for (int j = 0; j < 4; ++j) {
      if constexpr (WF32) bfrag[j] = ldfrag_f32(Wf + wrow[j] + ko);
      else                bfrag[j] = ldfrag_bf(Wb + wrow[j] + ko);
    }
    short8 afrag[2];
    if constexpr (MODE != 3) {
#pragma unroll
      for (int mi = 0; mi < 2; ++mi) {
        if constexpr (AF32) afrag[mi] = ldfrag_f32(Af + arow[mi] + ko);
        else                afrag[mi] = ldfrag_bf(Ab + arow[mi] + ko);
      }
    } else {
      int h = ko >> 6, e63 = ko & 63;
#pragma unroll
      for (int mi = 0; mi < 2; ++mi)
        afrag[mi] = ldfrag_bf(Ab + abase[mi] + (long)h * (SEQ * DKH) + e63);
    }
#pragma unroll
    for (int mi = 0; mi < 2; ++mi)
#pragma unroll
      for (int j = 0; j < 4; ++j)
        acc[mi][j] = __builtin_amdgcn_mfma_f32_16x16x32_bf16(afrag[mi], bfrag[j], acc[mi][j], 0, 0, 0);
  }

#pragma unroll
  for (int mi = 0; mi < 2; ++mi) {
#pragma unroll
    for (int j = 0; j < 4; ++j) {
#pragma unroll
      for (int r = 0; r < 4; ++r) {
        float v = acc[mi][j][r];
        int m = m0 + mi * 16 + q4 * 4 + r;
        int n = n0 + j * 16 + l16;
        if constexpr (MODE == 3) {
          reinterpret_cast<float*>(outp)[(long)m * DM + n] = v;
        } else {
          int b = m >> 11, s = m & 2047;
          int h = n >> 6, d = n & 63;
          long bh = (long)(b * NH + h);
          unsigned short* o = reinterpret_cast<unsigned short*>(outp);
          if constexpr (MODE == 0)      o[(bh * SEQ + s) * DKH + d] = f2b(v * 0.125f);
          else if constexpr (MODE == 1) o[(bh * SEQ + s) * DKH + d] = f2b(v);
          else                          o[(bh * DKH + d) * SEQ + s] = f2b(v);
        }
      }
    }
  }
}

// ---------------- workgroup-tiled flash attention, 32x32 MFMA, in-reg softmax
// Swapped QK^T (mfma(K,Q)) keeps the whole softmax row in registers; exp ->
// chop-to-bf16 -> pack -> permlane32_swap feeds PV A-frags directly (T12).
__global__ __launch_bounds__(256, 4) void attn_k(const unsigned short* __restrict__ Kbuf,
                                                 const unsigned short* __restrict__ Vt,
                                                 const unsigned short* __restrict__ Qbuf,
                                                 unsigned short* __restrict__ Obuf) {
  __shared__ unsigned short Kt[2][64 * 64];    // 16 KB, double-buffered K tile
  __shared__ unsigned short Vts[2][64 * 64];   // 16 KB, double-buffered V^T tile

  int t = threadIdx.x;
  int lane = t & 63;
  int w = t >> 6;
  int l31 = lane & 31, hi = lane >> 5;
  int qb = 15 - (blockIdx.x >> 6);             // heavy blocks first
  int bh = blockIdx.x & 63;
  int q0 = qb * 128;
  int qw0 = q0 + w * 32;                       // this wave's 32 q-rows

  const unsigned short* Qh = Qbuf + (long)bh * (SEQ * DKH);
  const unsigned short* Kh = Kbuf + (long)bh * (SEQ * DKH);
  const unsigned short* Vh = Vt   + (long)bh * (DKH * SEQ);

  // Q as B-fragment for swapped QK^T: lane holds Q[q=l31][d = dt*16 + hi*8 + j]
  short8 qf[4];
#pragma unroll
  for (int dt = 0; dt < 4; ++dt)
    qf[dt] = ldfrag_bf(Qh + (long)(qw0 + l31) * DKH + dt * 16 + hi * 8);

  f32x16 om[2];                                // O accum: row=q (crow), col=d
#pragma unroll
  for (int dv = 0; dv < 2; ++dv)
#pragma unroll
    for (int r = 0; r < 16; ++r) om[dv][r] = 0.f;
  float lsum = 0.f;                            // per-lane partial row-sum (q=l31)

  // K A-frag: row kr = sub*32+l31, d-chunk8 = dt*2+hi, XOR-swizzled slot
  int koff[2][4];
#pragma unroll
  for (int sub = 0; sub < 2; ++sub) {
    int kr = sub * 32 + l31;
#pragma unroll
    for (int dt = 0; dt < 4; ++dt)
      koff[sub][dt] = kr * 64 + ((dt * 2 + hi + kr + (kr >> 3)) & 7) * 8;
  }
  // V B-frag: row dr = dv*32+l31, k-chunk8 = kc*2+hi
  int voff[2][4];
#pragma unroll
  for (int dv = 0; dv < 2; ++dv) {
    int dr = dv * 32 + l31;
#pragma unroll
    for (int kc = 0; kc < 4; ++kc)
      voff[dv][kc] = dr * 64 + ((kc * 2 + hi + dr + (dr >> 3)) & 7) * 8;
  }

  // staging pointers (pre-swizzled global source, linear LDS dest)
  int rl0 = t >> 3, cp = t & 7;
  int rl1 = rl0 + 32;
  int sw0 = ((cp - rl0 - (rl0 >> 3)) & 7) * 8;
  int sw1 = ((cp - rl1 - (rl1 >> 3)) & 7) * 8;
  const unsigned short* kp0 = Kh + (long)rl0 * DKH + sw0;
  const unsigned short* kp1 = Kh + (long)rl1 * DKH + sw1;
  const unsigned short* vp0 = Vh + (long)rl0 * SEQ + sw0;
  const unsigned short* vp1 = Vh + (long)rl1 * SEQ + sw1;
  char* lK = (char*)Kt + t * 16;
  char* lV = (char*)Vts + t * 16;

  int nk = 2 * qb + 2;                         // 64-key tiles needed
  gl_lds16(kp0, lK); gl_lds16(kp1, lK + 4096);
  gl_lds16(vp0, lV); gl_lds16(vp1, lV + 4096);

  for (int it = 0; it < nk; ++it) {
    __syncthreads();                           // tile it staged
    if (it + 1 < nk) {
      kp0 += 64 * DKH; kp1 += 64 * DKH; vp0 += 64; vp1 += 64;
      int bo = ((it + 1) & 1) * 8192;
      gl_lds16(kp0, lK + bo); gl_lds16(kp1, lK + bo + 4096);
      gl_lds16(vp0, lV + bo); gl_lds16(vp1, lV + bo + 4096);
    }

    int k0 = it * 64;
    if (k0 <= qw0 + 31) {                      // wave-uniform causal activity
      const unsigned short* KT = Kt[0] + (it & 1) * 4096;
      const unsigned short* VT = Vts[0] + (it & 1) * 4096;

#pragma unroll
      for (int sub = 0; sub < 2; ++sub) {
        int ksb = k0 + sub * 32;
        if (ksb <= qw0 + 31) {                 // 32-key sub-tile active (uniform)
          // ---- swapped QK^T: S[k][q], col=q=l31, row=k=crow(r,hi)+ksb ----
          f32x16 s;
#pragma unroll
          for (int r = 0; r < 16; ++r) s[r] = 0.f;
#pragma unroll
          for (int dt = 0; dt < 4; ++dt) {
            short8 kf = ldfrag_bf(KT + koff[sub][dt]);
            s = __builtin_amdgcn_mfma_f32_32x32x16_bf16(kf, qf[dt], s, 0, 0, 0);
          }

          // ---- exp, causal mask, chop to bf16, pack k-pairs ----
          bool needmask = (ksb + 31 > qw0);
          int qr = qw0 + l31;
          unsigned int pk[4][2];               // [m][p]: k = 8m+4hi+2p+{0,1}
#pragma unroll
          for (int r = 0; r < 16; r += 2) {
            float p0 = __expf(s[r]);
            float p1 = __expf(s[r + 1]);
            if (needmask) {
              int key = ksb + (r & 3) + 8 * (r >> 2) + 4 * hi;
              p0 = (key <= qr) ? p0 : 0.f;
              p1 = (key + 1 <= qr) ? p1 : 0.f;
            }
            unsigned int u0 = __float_as_uint(p0) & 0xffff0000u;
            unsigned int u1 = __float_as_uint(p1) & 0xffff0000u;
            lsum += __uint_as_float(u0) + __uint_as_float(u1);  // sums the SAME
            pk[r >> 2][(r >> 1) & 1] = (u0 >> 16) | u1;         // chopped values
          }

          // ---- redistribute into PV A-frags: one swap fills two words ----
#pragma unroll
          for (int c = 0; c < 2; ++c) {
            u32x2 r0 = __builtin_amdgcn_permlane32_swap(pk[2 * c][0], pk[2 * c + 1][0], false, false);
            u32x2 r1 = __builtin_amdgcn_permlane32_swap(pk[2 * c][1], pk[2 * c + 1][1], false, false);
            u32x4 pw;
            pw.x = r0.x; pw.y = r1.x; pw.z = r0.y; pw.w = r1.y;
            short8 pa = __builtin_bit_cast(short8, pw);  // P[q=l31][k'=8hi+j]
            int kc = sub * 2 + c;
#pragma unroll
            for (int dv = 0; dv < 2; ++dv) {
              short8 vf = ldfrag_bf(VT + voff[dv][kc]);
              om[dv] = __builtin_amdgcn_mfma_f32_32x32x16_bf16(pa, vf, om[dv], 0, 0, 0);
            }
          }
        }
      }
    }
  }

  // ---- normalize: partner-sum lsum (lane l <-> l+32 share q=l31) ----
  u32x2 lz = __builtin_amdgcn_permlane32_swap(__float_as_uint(lsum), __float_as_uint(lsum),
                                              false, false);
  float inv = 1.f / (__uint_as_float(lz.x) + __uint_as_float(lz.y));  // for q=l31

  long obase = (long)bh * (SEQ * DKH);
#pragma unroll
  for (int r = 0; r < 16; ++r) {
    int qrow = (r & 3) + 8 * (r >> 2) + 4 * hi;   // om row -> q
    float invq = __shfl(inv, qrow);               // inv for that q lives at lane qrow
    long rowb = obase + (long)(qw0 + qrow) * DKH + l31;
    Obuf[rowb]      = f2b(om[0][r] * invq);
    Obuf[rowb + 32] = f2b(om[1][r] * invq);
  }
}

extern "C" void kernel_launch(void* const* d_in, const int* in_sizes, int n_in,
                              void* d_out, int out_size, void* d_ws, size_t ws_size,
                              hipStream_t stream) {
  const float* x  = (const float*)d_in[0];
  const float* wq = (const float*)d_in[1];
  const float* wk = (const float*)d_in[2];
  const float* wv = (const float*)d_in[3];
  const float* wo = (const float*)d_in[4];

  // Q/K bf16 staged in d_out (exactly 16M ushorts); final GEMM overwrites with fp32.
  unsigned short* Qb = (unsigned short*)d_out;
  unsigned short* Kb = Qb + 8388608;

  if (ws_size >= 41943040ull) {
    // ---- fast path (>=40 MiB ws): xb 16 MiB | weights 8 MiB | Vt 16 MiB ----
    unsigned short* xb  = (unsigned short*)d_ws;   // becomes O after projections
    unsigned short* wqb = xb + 8388608;
    unsigned short* wkb = wqb + 1048576;
    unsigned short* wvb = wkb + 1048576;
    unsigned short* wob = wvb + 1048576;
    unsigned short* Vt  = wob + 1048576;           // [B,H,dk,S]
    unsigned short* Ob  = xb;

    cast_all<<<12288, 256, 0, stream>>>(x, wq, wk, wv, wo, xb, wqb, wkb, wvb, wob);

    gemm_qkv<<<1536, 256, 0, stream>>>(xb, wqb, wkb, wvb, Qb, Kb, Vt);
    attn_k<<<1024, 256, 0, stream>>>(Kb, Vt, Qb, Ob);
    gemm_o<<<512, 256, 0, stream>>>(Ob, wob, (float*)d_out);
  } else if (ws_size >= 33554432ull) {
    // ---- minimal path (32 MiB ws): fp32 direct gemms, fast attention ----
    unsigned short* Vt = (unsigned short*)d_ws;   // 8M els [B,H,dk,S]
    unsigned short* Ob = Vt + 8388608;            // 8M els [B,H,S,dk]

    gemm_s<0, true, true><<<1024, 256, 0, stream>>>(x, wq, Qb);
    gemm_s<1, true, true><<<1024, 256, 0, stream>>>(x, wk, Kb);
    gemm_s<2, true, true><<<1024, 256, 0, stream>>>(x, wv, Vt);
    attn_k<<<1024, 256, 0, stream>>>(Kb, Vt, Qb, Ob);
    gemm_s<3, false, true><<<1024, 256, 0, stream>>>(Ob, wo, d_out);
  } else {
    zero_f32<<<8192, 256, 0, stream>>>((float*)d_out, 2097152);
  }
}

// Round 4
// 248.612 us; speedup vs baseline: 1.0136x; 1.0136x over previous
//
#include <hip/hip_runtime.h>

#define SEQ 2048
#define DM 1024
#define NH 16
#define DKH 64
// M rows total = 4*2048 = 8192

typedef __attribute__((ext_vector_type(8))) short short8;   // 8 bf16
typedef __attribute__((ext_vector_type(4))) float f32x4;
typedef __attribute__((ext_vector_type(16))) float f32x16;
typedef __attribute__((ext_vector_type(2))) unsigned int u32x2;
typedef __attribute__((ext_vector_type(4))) unsigned int u32x4;

static __device__ __forceinline__ unsigned short f2b(float f) {
  unsigned int u = __float_as_uint(f);
  u += 0x7fffu + ((u >> 16) & 1u);   // round-to-nearest-even
  return (unsigned short)(u >> 16);
}

static __device__ __forceinline__ short8 ldfrag_bf(const unsigned short* p) {
  return *reinterpret_cast<const short8*>(p);
}
static __device__ __forceinline__ short8 ldfrag_f32(const float* p) {
  const float4* q = reinterpret_cast<const float4*>(p);
  float4 a = q[0], b = q[1];
  short8 r;
  r[0] = (short)f2b(a.x); r[1] = (short)f2b(a.y);
  r[2] = (short)f2b(a.z); r[3] = (short)f2b(a.w);
  r[4] = (short)f2b(b.x); r[5] = (short)f2b(b.y);
  r[6] = (short)f2b(b.z); r[7] = (short)f2b(b.w);
  return r;
}

// async global->LDS, 16 B per lane. LDS side MUST be wave-uniform base + lane*16.
static __device__ __forceinline__ void gl_lds16(const void* g, void* l) {
  __builtin_amdgcn_global_load_lds(
      (const __attribute__((address_space(1))) unsigned int*)g,
      (__attribute__((address_space(3))) unsigned int*)l, 16, 0, 0);
}

__global__ __launch_bounds__(256) void zero_f32(float* __restrict__ p, int n4) {
  int i = blockIdx.x * 256 + threadIdx.x;
  if (i < n4) {
    float4 z = {0.f, 0.f, 0.f, 0.f};
    reinterpret_cast<float4*>(p)[i] = z;
  }
}

// fused cast: blocks [0,8192) cast x (2M float4s); blocks [8192,12288) cast the
// 4 weight matrices (1024 blocks each). wq pre-scaled by 0.125 (exact pow-2).
__global__ __launch_bounds__(256) void cast_all(const float* __restrict__ x,
                                                const float* __restrict__ a, const float* __restrict__ b,
                                                const float* __restrict__ c, const float* __restrict__ d,
                                                unsigned short* __restrict__ xo,
                                                unsigned short* __restrict__ oa, unsigned short* __restrict__ ob,
                                                unsigned short* __restrict__ oc, unsigned short* __restrict__ od) {
  int blk = blockIdx.x;
  if (blk < 8192) {
    int i = blk * 256 + threadIdx.x;
    float4 v = reinterpret_cast<const float4*>(x)[i];
    ushort4 o;
    o.x = f2b(v.x); o.y = f2b(v.y); o.z = f2b(v.z); o.w = f2b(v.w);
    reinterpret_cast<ushort4*>(xo)[i] = o;
  } else {
    blk -= 8192;
    int which = blk >> 10;
    int i = (blk & 1023) * 256 + threadIdx.x;   // [0, 262144) float4s
    const float* s = (which == 0) ? a : (which == 1) ? b : (which == 2) ? c : d;
    unsigned short* o = (which == 0) ? oa : (which == 1) ? ob : (which == 2) ? oc : od;
    float sc = (which == 0) ? 0.125f : 1.0f;
    float4 v = reinterpret_cast<const float4*>(s)[i];
    ushort4 u;
    u.x = f2b(v.x * sc); u.y = f2b(v.y * sc); u.z = f2b(v.z * sc); u.w = f2b(v.w * sc);
    reinterpret_cast<ushort4*>(o)[i] = u;
  }
}

// ---------------- fused QKV GEMM: 128x128 tiles, BK=32 ----------------------
// Depth-2 prefetch: 3 LDS buffers, loads for step ks+2 issued at step ks, raw
// s_barrier + counted vmcnt(4) (never 0 in steady state) so each buffer's
// loads get ~2 K-steps of cover instead of 1 (T4: loads span barriers).
__global__ __launch_bounds__(256) void gemm_qkv(const unsigned short* __restrict__ A,
                                                const unsigned short* __restrict__ Wq,
                                                const unsigned short* __restrict__ Wk,
                                                const unsigned short* __restrict__ Wv,
                                                unsigned short* __restrict__ Qb,
                                                unsigned short* __restrict__ Kb,
                                                unsigned short* __restrict__ Vt) {
  __shared__ char smem[49152];
  unsigned short* At = (unsigned short*)smem;             // 3 bufs x 8 KB
  unsigned short* Wt = (unsigned short*)(smem + 24576);   // 3 bufs x 8 KB
  int t = threadIdx.x;
  int lane = t & 63;
  int w = t >> 6;
  int l16 = lane & 15, q4 = lane >> 4;
  int mode = blockIdx.x % 3;
  int bid = blockIdx.x / 3;
  int mt = bid >> 3, nt = bid & 7;
  int m0 = mt * 128, n0 = nt * 128;
  int mw = (w & 1) * 64, nw = (w >> 1) * 64;
  const unsigned short* W = (mode == 0) ? Wq : (mode == 1) ? Wk : Wv;

  const f32x4 zero4 = {0.f, 0.f, 0.f, 0.f};
  f32x4 acc[4][4];
#pragma unroll
  for (int mi = 0; mi < 4; ++mi)
#pragma unroll
    for (int nj = 0; nj < 4; ++nj) acc[mi][nj] = zero4;

  // staging pointers (advance by 32 ushorts per K-step); source pre-swizzle
  // must be the same involution as the read-side chunk swizzle.
  int rl0 = t >> 2, cp = t & 3;
  int rl1 = rl0 + 64;
  int sw0 = ((cp - rl0 - (rl0 >> 2)) & 3) * 8;
  int sw1 = ((cp - rl1 - (rl1 >> 2)) & 3) * 8;
  const unsigned short* ga0 = A + (long)(m0 + rl0) * DM + sw0;
  const unsigned short* ga1 = A + (long)(m0 + rl1) * DM + sw1;
  const unsigned short* gw0 = W + (long)(n0 + rl0) * DM + sw0;
  const unsigned short* gw1 = W + (long)(n0 + rl1) * DM + sw1;
  char* lA = (char*)At + t * 16;
  char* lW = (char*)Wt + t * 16;

  // hoisted fragment LDS offsets (loop-invariant)
  int aoff[4], woff[4];
#pragma unroll
  for (int mi = 0; mi < 4; ++mi) {
    int r = mw + mi * 16 + l16;
    aoff[mi] = r * 32 + ((q4 + r + (r >> 2)) & 3) * 8;
  }
#pragma unroll
  for (int nj = 0; nj < 4; ++nj) {
    int r = nw + nj * 16 + l16;
    woff[nj] = r * 32 + ((q4 + r + (r >> 2)) & 3) * 8;
  }

  auto issue = [&](int boB) {
    gl_lds16(ga0, lA + boB); gl_lds16(ga1, lA + boB + 4096);
    gl_lds16(gw0, lW + boB); gl_lds16(gw1, lW + boB + 4096);
    ga0 += 32; ga1 += 32; gw0 += 32; gw1 += 32;
  };

  // prologue: steps 0 and 1 in flight; wait for step 0 only (vmcnt(4))
  issue(0);
  issue(8192);
  __asm__ volatile("s_waitcnt vmcnt(4)" ::: "memory");
  __builtin_amdgcn_sched_barrier(0);
  __builtin_amdgcn_s_barrier();
  __builtin_amdgcn_sched_barrier(0);

  int cbB = 0, pbB = 16384;                 // compute / prefetch buffer (bytes)
  for (int ks = 0; ks < 32; ++ks) {
    if (ks < 30) issue(pbB);                // step ks+2 -> third buffer

    const unsigned short* Ab = (const unsigned short*)((char*)At + cbB);
    const unsigned short* Wb = (const unsigned short*)((char*)Wt + cbB);
    short8 af[4], wf[4];
#pragma unroll
    for (int mi = 0; mi < 4; ++mi) af[mi] = ldfrag_bf(Ab + aoff[mi]);
#pragma unroll
    for (int nj = 0; nj < 4; ++nj) wf[nj] = ldfrag_bf(Wb + woff[nj]);
#pragma unroll
    for (int mi = 0; mi < 4; ++mi)
#pragma unroll
      for (int nj = 0; nj < 4; ++nj)
        acc[mi][nj] = __builtin_amdgcn_mfma_f32_16x16x32_bf16(af[mi], wf[nj], acc[mi][nj], 0, 0, 0);

    if (ks < 31) {
      if (ks < 30) { __asm__ volatile("s_waitcnt vmcnt(4)" ::: "memory"); }
      else         { __asm__ volatile("s_waitcnt vmcnt(0)" ::: "memory"); }
      __builtin_amdgcn_sched_barrier(0);
      __builtin_amdgcn_s_barrier();
      __builtin_amdgcn_sched_barrier(0);
    }
    cbB += 8192; if (cbB == 24576) cbB = 0;
    pbB += 8192; if (pbB == 24576) pbB = 0;
  }

  if (mode != 2) {
    // Q/K: [B,H,S,dk]. b,h wave-constant -> single base + immediate offsets.
    unsigned short* o = (mode == 0) ? Qb : Kb;
    int b = m0 >> 11;
    int h = (n0 + nw) >> 6;
    long bh0 = (long)(b * NH + h);
    unsigned short* op = o + (bh0 * SEQ + (m0 & 2047) + mw + q4 * 4) * DKH + l16;
#pragma unroll
    for (int mi = 0; mi < 4; ++mi)
#pragma unroll
      for (int nj = 0; nj < 4; ++nj)
#pragma unroll
        for (int r = 0; r < 4; ++r)
          op[mi * 1024 + r * 64 + nj * 16] = f2b(acc[mi][nj][r]);
  } else {
    // V^T via LDS: wave tile = 64 s-rows x 64 d-cols (exactly one head)
    __syncthreads();                       // everyone done reading K-loop LDS
    unsigned short* vle = (unsigned short*)(smem + w * 8192);   // 64x64 ushorts
    unsigned int* vle32 = (unsigned int*)vle;
#pragma unroll
    for (int nj = 0; nj < 4; ++nj) {
      int d = nj * 16 + l16;
      int k8 = (d & 7) * 8;
#pragma unroll
      for (int mi = 0; mi < 4; ++mi)
#pragma unroll
        for (int r = 0; r < 4; r += 2) {
          int s = mi * 16 + q4 * 4 + r;
          unsigned int pk = (unsigned int)f2b(acc[mi][nj][r]) |
                            ((unsigned int)f2b(acc[mi][nj][r + 1]) << 16);
          vle32[d * 32 + ((s ^ k8) >> 1)] = pk;   // XOR chunk swizzle
        }
    }
    __asm__ volatile("s_waitcnt lgkmcnt(0)" ::: "memory");  // wave-local round-trip
    int b = m0 >> 11;
    int h = (n0 + nw) >> 6;
    long bh = (long)(b * NH + h);
    int sbase = (m0 + mw) & 2047;          // within-batch seq index
    int dr_lo = lane >> 3, c = lane & 7;
    // (dr & 7) == dr_lo for every pass -> read offset is pass-invariant + imm
    const unsigned short* vr = vle + dr_lo * 64 + (c ^ dr_lo) * 8;
    unsigned short* vtp = Vt + (bh * DKH + dr_lo) * SEQ + sbase + c * 8;
#pragma unroll
    for (int pass = 0; pass < 8; ++pass) {
      short8 vv = ldfrag_bf(vr + pass * 512);
      *reinterpret_cast<short8*>(vtp + (long)pass * 8 * SEQ) = vv;
    }
  }
}

// ---------------- O-projection GEMM, depth-2 prefetch, 3-buffer -------------
__global__ __launch_bounds__(256) void gemm_o(const unsigned short* __restrict__ A,
                                              const unsigned short* __restrict__ W,
                                              float* __restrict__ outp) {
  __shared__ char smem[49152];
  unsigned short* At = (unsigned short*)smem;
  unsigned short* Wt = (unsigned short*)(smem + 24576);
  int t = threadIdx.x;
  int lane = t & 63;
  int w = t >> 6;
  int l16 = lane & 15, q4 = lane >> 4;
  // bijective XCD swizzle: 512 blocks = 8 XCDs x 64
  int swz = (blockIdx.x & 7) * 64 + (blockIdx.x >> 3);
  int mt = swz >> 3, nt = swz & 7;
  int m0 = mt * 128, n0 = nt * 128;
  int mw = (w & 1) * 64, nw = (w >> 1) * 64;

  const f32x4 zero4 = {0.f, 0.f, 0.f, 0.f};
  f32x4 acc[4][4];
#pragma unroll
  for (int mi = 0; mi < 4; ++mi)
#pragma unroll
    for (int nj = 0; nj < 4; ++nj) acc[mi][nj] = zero4;

  int rl0 = t >> 2, cp = t & 3;
  int rl1 = rl0 + 64;
  int sw0 = ((cp - rl0 - (rl0 >> 2)) & 3) * 8;
  int sw1 = ((cp - rl1 - (rl1 >> 2)) & 3) * 8;
  // A is [B,H,S,dk] head-chunked: k advances 32 within a head, then hops heads
  int b0 = m0 >> 11;
  const unsigned short* ga0;
  const unsigned short* ga1;
  {
    int s0 = (m0 & 2047) + rl0;
    ga0 = A + (long)b0 * (NH * SEQ * DKH) + (long)s0 * DKH + sw0;
    int s1 = (m0 & 2047) + rl1;
    ga1 = A + (long)b0 * (NH * SEQ * DKH) + (long)s1 * DKH + sw1;
  }
  const unsigned short* gw0 = W + (long)(n0 + rl0) * DM + sw0;
  const unsigned short* gw1 = W + (long)(n0 + rl1) * DM + sw1;
  char* lA = (char*)At + t * 16;
  char* lW = (char*)Wt + t * 16;

  int aoff[4], woff[4];
#pragma unroll
  for (int mi = 0; mi < 4; ++mi) {
    int r = mw + mi * 16 + l16;
    aoff[mi] = r * 32 + ((q4 + r + (r >> 2)) & 3) * 8;
  }
#pragma unroll
  for (int nj = 0; nj < 4; ++nj) {
    int r = nw + nj * 16 + l16;
    woff[nj] = r * 32 + ((q4 + r + (r >> 2)) & 3) * 8;
  }

  int js = 0;                                 // next step index to issue
  auto issue = [&](int boB) {
    gl_lds16(ga0, lA + boB); gl_lds16(ga1, lA + boB + 4096);
    gl_lds16(gw0, lW + boB); gl_lds16(gw1, lW + boB + 4096);
    int adv = ((js & 1) == 0) ? 32 : (SEQ * DKH - 32);   // head-hop on odd js
    ga0 += adv; ga1 += adv; gw0 += 32; gw1 += 32;
    ++js;
  };

  issue(0);
  issue(8192);
  __asm__ volatile("s_waitcnt vmcnt(4)" ::: "memory");
  __builtin_amdgcn_sched_barrier(0);
  __builtin_amdgcn_s_barrier();
  __builtin_amdgcn_sched_barrier(0);

  int cbB = 0, pbB = 16384;
  for (int ks = 0; ks < 32; ++ks) {
    if (ks < 30) issue(pbB);

    const unsigned short* Ab = (const unsigned short*)((char*)At + cbB);
    const unsigned short* Wb = (const unsigned short*)((char*)Wt + cbB);
    short8 af[4], wf[4];
#pragma unroll
    for (int mi = 0; mi < 4; ++mi) af[mi] = ldfrag_bf(Ab + aoff[mi]);
#pragma unroll
    for (int nj = 0; nj < 4; ++nj) wf[nj] = ldfrag_bf(Wb + woff[nj]);
#pragma unroll
    for (int mi = 0; mi < 4; ++mi)
#pragma unroll
      for (int nj = 0; nj < 4; ++nj)
        acc[mi][nj] = __builtin_amdgcn_mfma_f32_16x16x32_bf16(af[mi], wf[nj], acc[mi][nj], 0, 0, 0);

    if (ks < 31) {
      if (ks < 30) { __asm__ volatile("s_waitcnt vmcnt(4)" ::: "memory"); }
      else         { __asm__ volatile("s_waitcnt vmcnt(0)" ::: "memory"); }
      __builtin_amdgcn_sched_barrier(0);
      __builtin_amdgcn_s_barrier();
      __builtin_amdgcn_sched_barrier(0);
    }
    cbB += 8192; if (cbB == 24576) cbB = 0;
    pbB += 8192; if (pbB == 24576) pbB = 0;
  }

  // hoisted epilogue: one base, compile-time offsets
  {
    float* op = outp + (long)(m0 + mw + q4 * 4) * DM + n0 + nw + l16;
#pragma unroll
    for (int mi = 0; mi < 4; ++mi)
#pragma unroll
      for (int nj = 0; nj < 4; ++nj)
#pragma unroll
        for (int r = 0; r < 4; ++r)
          op[(mi * 16 + r) * DM + nj * 16] = acc[mi][nj][r];
  }
}

// ---------------- slow GEMM (direct-global, fp32 cvt) — small-ws fallback ----
template<int MODE, bool AF32, bool WF32>
__global__ __launch_bounds__(256) void gemm_s(const void* __restrict__ Ap,
                                              const void* __restrict__ Wp,
                                              void* __restrict__ outp) {
  int wid  = (blockIdx.x * 256 + threadIdx.x) >> 6;
  int lane = threadIdx.x & 63;
  int l16  = lane & 15, q4 = lane >> 4;
  int tn = wid & 15, tm = wid >> 4;
  int m0 = tm * 32, n0 = tn * 64;

  const float*          Af = (const float*)Ap;
  const unsigned short* Ab = (const unsigned short*)Ap;
  const float*          Wf = (const float*)Wp;
  const unsigned short* Wb = (const unsigned short*)Wp;

  const f32x4 zero4 = {0.f, 0.f, 0.f, 0.f};
  f32x4 acc[2][4];
#pragma unroll
  for (int mi = 0; mi < 2; ++mi)
#pragma unroll
    for (int j = 0; j < 4; ++j) acc[mi][j] = zero4;

  int wrow[4];
#pragma unroll
  for (int j = 0; j < 4; ++j) wrow[j] = (n0 + j * 16 + l16) * DM;
  int arow[2] = {0, 0};
  long abase[2] = {0, 0};
  if (MODE != 3) {
#pragma unroll
    for (int mi = 0; mi < 2; ++mi) arow[mi] = (m0 + mi * 16 + l16) * DM;
  } else {
    int b = m0 >> 11;
#pragma unroll
    for (int mi = 0; mi < 2; ++mi) {
      int srow = (m0 & 2047) + mi * 16 + l16;
      abase[mi] = (long)b * (NH * SEQ * DKH) + (long)srow * DKH;
    }
  }

#pragma unroll 2
  for (int ks = 0; ks < 32; ++ks) {
    int ko = ks * 32 + q4 * 8;
    short8 bfrag[4];
#pragma unroll
    for (int j = 0; j < 4; ++j) {
      if constexpr (WF32) bfrag[j] = ldfrag_f32(Wf + wrow[j] + ko);
      else                bfrag[j] = ldfrag_bf(Wb + wrow[j] + ko);
    }
    short8 afrag[2];
    if constexpr (MODE != 3) {
#pragma unroll
      for (int mi = 0; mi < 2; ++mi) {
        if constexpr (AF32) afrag[mi] = ldfrag_f32(Af + arow[mi] + ko);
        else                afrag[mi] = ldfrag_bf(Ab + arow[mi] + ko);
      }
    } else {
      int h = ko >> 6, e63 = ko & 63;
#pragma unroll
      for (int mi = 0; mi < 2; ++mi)
        afrag[mi] = ldfrag_bf(Ab + abase[mi] + (long)h * (SEQ * DKH) + e63);
    }
#pragma unroll
    for (int mi = 0; mi < 2; ++mi)
#pragma unroll
      for (int j = 0; j < 4; ++j)
        acc[mi][j] = __builtin_amdgcn_mfma_f32_16x16x32_bf16(afrag[mi], bfrag[j], acc[mi][j], 0, 0, 0);
  }

#pragma unroll
  for (int mi = 0; mi < 2; ++mi) {
#pragma unroll
    for (int j = 0; j < 4; ++j) {
#pragma unroll
      for (int r = 0; r < 4; ++r) {
        float v = acc[mi][j][r];
        int m = m0 + mi * 16 + q4 * 4 + r;
        int n = n0 + j * 16 + l16;
        if constexpr (MODE == 3) {
          reinterpret_cast<float*>(outp)[(long)m * DM + n] = v;
        } else {
          int b = m >> 11, s = m & 2047;
          int h = n >> 6, d = n & 63;
          long bh = (long)(b * NH + h);
          unsigned short* o = reinterpret_cast<unsigned short*>(outp);
          if constexpr (MODE == 0)      o[(bh * SEQ + s) * DKH + d] = f2b(v * 0.125f);
          else if constexpr (MODE == 1) o[(bh * SEQ + s) * DKH + d] = f2b(v);
          else                          o[(bh * DKH + d) * SEQ + s] = f2b(v);
        }
      }
    }
  }
}

// ---------------- workgroup-tiled flash attention, 32x32 MFMA, in-reg softmax
// Swapped QK^T (mfma(K,Q)) keeps the whole softmax row in registers; exp ->
// chop-to-bf16 -> pack -> permlane32_swap feeds PV A-frags directly (T12).
__global__ __launch_bounds__(256, 4) void attn_k(const unsigned short* __restrict__ Kbuf,
                                                 const unsigned short* __restrict__ Vt,
                                                 const unsigned short* __restrict__ Qbuf,
                                                 unsigned short* __restrict__ Obuf) {
  __shared__ unsigned short Kt[2][64 * 64];    // 16 KB, double-buffered K tile
  __shared__ unsigned short Vts[2][64 * 64];   // 16 KB, double-buffered V^T tile

  int t = threadIdx.x;
  int lane = t & 63;
  int w = t >> 6;
  int l31 = lane & 31, hi = lane >> 5;
  int qb = 15 - (blockIdx.x >> 6);             // heavy blocks first
  int bh = blockIdx.x & 63;
  int q0 = qb * 128;
  int qw0 = q0 + w * 32;                       // this wave's 32 q-rows

  const unsigned short* Qh = Qbuf + (long)bh * (SEQ * DKH);
  const unsigned short* Kh = Kbuf + (long)bh * (SEQ * DKH);
  const unsigned short* Vh = Vt   + (long)bh * (DKH * SEQ);

  // Q as B-fragment for swapped QK^T: lane holds Q[q=l31][d = dt*16 + hi*8 + j]
  short8 qf[4];
#pragma unroll
  for (int dt = 0; dt < 4; ++dt)
    qf[dt] = ldfrag_bf(Qh + (long)(qw0 + l31) * DKH + dt * 16 + hi * 8);

  f32x16 om[2];                                // O accum: row=q (crow), col=d
#pragma unroll
  for (int dv = 0; dv < 2; ++dv)
#pragma unroll
    for (int r = 0; r < 16; ++r) om[dv][r] = 0.f;
  float lsum = 0.f;                            // per-lane partial row-sum (q=l31)

  // K A-frag: row kr = sub*32+l31, d-chunk8 = dt*2+hi, XOR-swizzled slot
  int koff[2][4];
#pragma unroll
  for (int sub = 0; sub < 2; ++sub) {
    int kr = sub * 32 + l31;
#pragma unroll
    for (int dt = 0; dt < 4; ++dt)
      koff[sub][dt] = kr * 64 + ((dt * 2 + hi + kr + (kr >> 3)) & 7) * 8;
  }
  // V B-frag: row dr = dv*32+l31, k-chunk8 = kc*2+hi
  int voff[2][4];
#pragma unroll
  for (int dv = 0; dv < 2; ++dv) {
    int dr = dv * 32 + l31;
#pragma unroll
    for (int kc = 0; kc < 4; ++kc)
      voff[dv][kc] = dr * 64 + ((kc * 2 + hi + dr + (dr >> 3)) & 7) * 8;
  }

  // staging pointers (pre-swizzled global source, linear LDS dest)
  int rl0 = t >> 3, cp = t & 7;
  int rl1 = rl0 + 32;
  int sw0 = ((cp - rl0 - (rl0 >> 3)) & 7) * 8;
  int sw1 = ((cp - rl1 - (rl1 >> 3)) & 7) * 8;
  const unsigned short* kp0 = Kh + (long)rl0 * DKH + sw0;
  const unsigned short* kp1 = Kh + (long)rl1 * DKH + sw1;
  const unsigned short* vp0 = Vh + (long)rl0 * SEQ + sw0;
  const unsigned short* vp1 = Vh + (long)rl1 * SEQ + sw1;
  char* lK = (char*)Kt + t * 16;
  char* lV = (char*)Vts + t * 16;

  int nk = 2 * qb + 2;                         // 64-key tiles needed
  gl_lds16(kp0, lK); gl_lds16(kp1, lK + 4096);
  gl_lds16(vp0, lV); gl_lds16(vp1, lV + 4096);

  for (int it = 0; it < nk; ++it) {
    __syncthreads();                           // tile it staged
    if (it + 1 < nk) {
      kp0 += 64 * DKH; kp1 += 64 * DKH; vp0 += 64; vp1 += 64;
      int bo = ((it + 1) & 1) * 8192;
      gl_lds16(kp0, lK + bo); gl_lds16(kp1, lK + bo + 4096);
      gl_lds16(vp0, lV + bo); gl_lds16(vp1, lV + bo + 4096);
    }

    int k0 = it * 64;
    if (k0 <= qw0 + 31) {                      // wave-uniform causal activity
      const unsigned short* KT = Kt[0] + (it & 1) * 4096;
      const unsigned short* VT = Vts[0] + (it & 1) * 4096;

#pragma unroll
      for (int sub = 0; sub < 2; ++sub) {
        int ksb = k0 + sub * 32;
        if (ksb <= qw0 + 31) {                 // 32-key sub-tile active (uniform)
          // ---- swapped QK^T: S[k][q], col=q=l31, row=k=crow(r,hi)+ksb ----
          f32x16 s;
#pragma unroll
          for (int r = 0; r < 16; ++r) s[r] = 0.f;
#pragma unroll
          for (int dt = 0; dt < 4; ++dt) {
            short8 kf = ldfrag_bf(KT + koff[sub][dt]);
            s = __builtin_amdgcn_mfma_f32_32x32x16_bf16(kf, qf[dt], s, 0, 0, 0);
          }

          // ---- exp, causal mask, chop to bf16, pack k-pairs ----
          bool needmask = (ksb + 31 > qw0);
          int qr = qw0 + l31;
          unsigned int pk[4][2];               // [m][p]: k = 8m+4hi+2p+{0,1}
#pragma unroll
          for (int r = 0; r < 16; r += 2) {
            float p0 = __expf(s[r]);
            float p1 = __expf(s[r + 1]);
            if (needmask) {
              int key = ksb + (r & 3) + 8 * (r >> 2) + 4 * hi;
              p0 = (key <= qr) ? p0 : 0.f;
              p1 = (key + 1 <= qr) ? p1 : 0.f;
            }
            unsigned int u0 = __float_as_uint(p0) & 0xffff0000u;
            unsigned int u1 = __float_as_uint(p1) & 0xffff0000u;
            lsum += __uint_as_float(u0) + __uint_as_float(u1);  // sums the SAME
            pk[r >> 2][(r >> 1) & 1] = (u0 >> 16) | u1;         // chopped values
          }

          // ---- redistribute into PV A-frags: one swap fills two words ----
#pragma unroll
          for (int c = 0; c < 2; ++c) {
            u32x2 r0 = __builtin_amdgcn_permlane32_swap(pk[2 * c][0], pk[2 * c + 1][0], false, false);
            u32x2 r1 = __builtin_amdgcn_permlane32_swap(pk[2 * c][1], pk[2 * c + 1][1], false, false);
            u32x4 pw;
            pw.x = r0.x; pw.y = r1.x; pw.z = r0.y; pw.w = r1.y;
            short8 pa = __builtin_bit_cast(short8, pw);  // P[q=l31][k'=8hi+j]
            int kc = sub * 2 + c;
#pragma unroll
            for (int dv = 0; dv < 2; ++dv) {
              short8 vf = ldfrag_bf(VT + voff[dv][kc]);
              om[dv] = __builtin_amdgcn_mfma_f32_32x32x16_bf16(pa, vf, om[dv], 0, 0, 0);
            }
          }
        }
      }
    }
  }

  // ---- normalize: partner-sum lsum (lane l <-> l+32 share q=l31) ----
  u32x2 lz = __builtin_amdgcn_permlane32_swap(__float_as_uint(lsum), __float_as_uint(lsum),
                                              false, false);
  float inv = 1.f / (__uint_as_float(lz.x) + __uint_as_float(lz.y));  // for q=l31

  long obase = (long)bh * (SEQ * DKH);
#pragma unroll
  for (int r = 0; r < 16; ++r) {
    int qrow = (r & 3) + 8 * (r >> 2) + 4 * hi;   // om row -> q
    float invq = __shfl(inv, qrow);               // inv for that q lives at lane qrow
    long rowb = obase + (long)(qw0 + qrow) * DKH + l31;
    Obuf[rowb]      = f2b(om[0][r] * invq);
    Obuf[rowb + 32] = f2b(om[1][r] * invq);
  }
}

extern "C" void kernel_launch(void* const* d_in, const int* in_sizes, int n_in,
                              void* d_out, int out_size, void* d_ws, size_t ws_size,
                              hipStream_t stream) {
  const float* x  = (const float*)d_in[0];
  const float* wq = (const float*)d_in[1];
  const float* wk = (const float*)d_in[2];
  const float* wv = (const float*)d_in[3];
  const float* wo = (const float*)d_in[4];

  // Q/K bf16 staged in d_out (exactly 16M ushorts); final GEMM overwrites with fp32.
  unsigned short* Qb = (unsigned short*)d_out;
  unsigned short* Kb = Qb + 8388608;

  if (ws_size >= 41943040ull) {
    // ---- fast path (>=40 MiB ws): xb 16 MiB | weights 8 MiB | Vt 16 MiB ----
    unsigned short* xb  = (unsigned short*)d_ws;   // becomes O after projections
    unsigned short* wqb = xb + 8388608;
    unsigned short* wkb = wqb + 1048576;
    unsigned short* wvb = wkb + 1048576;
    unsigned short* wob = wvb + 1048576;
    unsigned short* Vt  = wob + 1048576;           // [B,H,dk,S]
    unsigned short* Ob  = xb;

    cast_all<<<12288, 256, 0, stream>>>(x, wq, wk, wv, wo, xb, wqb, wkb, wvb, wob);

    gemm_qkv<<<1536, 256, 0, stream>>>(xb, wqb, wkb, wvb, Qb, Kb, Vt);
    attn_k<<<1024, 256, 0, stream>>>(Kb, Vt, Qb, Ob);
    gemm_o<<<512, 256, 0, stream>>>(Ob, wob, (float*)d_out);
  } else if (ws_size >= 33554432ull) {
    // ---- minimal path (32 MiB ws): fp32 direct gemms, fast attention ----
    unsigned short* Vt = (unsigned short*)d_ws;   // 8M els [B,H,dk,S]
    unsigned short* Ob = Vt + 8388608;            // 8M els [B,H,S,dk]

    gemm_s<0, true, true><<<1024, 256, 0, stream>>>(x, wq, Qb);
    gemm_s<1, true, true><<<1024, 256, 0, stream>>>(x, wk, Kb);
    gemm_s<2, true, true><<<1024, 256, 0, stream>>>(x, wv, Vt);
    attn_k<<<1024, 256, 0, stream>>>(Kb, Vt, Qb, Ob);
    gemm_s<3, false, true><<<1024, 256, 0, stream>>>(Ob, wo, d_out);
  } else {
    zero_f32<<<8192, 256, 0, stream>>>((float*)d_out, 2097152);
  }
}

// Round 5
// 232.942 us; speedup vs baseline: 1.0818x; 1.0673x over previous
//
#include <hip/hip_runtime.h>

#define SEQ 2048
#define DM 1024
#define NH 16
#define DKH 64
// M rows total = 4*2048 = 8192

typedef __attribute__((ext_vector_type(8))) short short8;   // 8 bf16
typedef __attribute__((ext_vector_type(4))) float f32x4;
typedef __attribute__((ext_vector_type(16))) float f32x16;
typedef __attribute__((ext_vector_type(2))) unsigned int u32x2;
typedef __attribute__((ext_vector_type(4))) unsigned int u32x4;

static __device__ __forceinline__ unsigned short f2b(float f) {
  unsigned int u = __float_as_uint(f);
  u += 0x7fffu + ((u >> 16) & 1u);   // round-to-nearest-even
  return (unsigned short)(u >> 16);
}

static __device__ __forceinline__ short8 ldfrag_bf(const unsigned short* p) {
  return *reinterpret_cast<const short8*>(p);
}
static __device__ __forceinline__ short8 ldfrag_f32(const float* p) {
  const float4* q = reinterpret_cast<const float4*>(p);
  float4 a = q[0], b = q[1];
  short8 r;
  r[0] = (short)f2b(a.x); r[1] = (short)f2b(a.y);
  r[2] = (short)f2b(a.z); r[3] = (short)f2b(a.w);
  r[4] = (short)f2b(b.x); r[5] = (short)f2b(b.y);
  r[6] = (short)f2b(b.z); r[7] = (short)f2b(b.w);
  return r;
}

// async global->LDS, 16 B per lane. LDS side MUST be wave-uniform base + lane*16.
static __device__ __forceinline__ void gl_lds16(const void* g, void* l) {
  __builtin_amdgcn_global_load_lds(
      (const __attribute__((address_space(1))) unsigned int*)g,
      (__attribute__((address_space(3))) unsigned int*)l, 16, 0, 0);
}

__global__ __launch_bounds__(256) void zero_f32(float* __restrict__ p, int n4) {
  int i = blockIdx.x * 256 + threadIdx.x;
  if (i < n4) {
    float4 z = {0.f, 0.f, 0.f, 0.f};
    reinterpret_cast<float4*>(p)[i] = z;
  }
}

// fused cast: blocks [0,8192) cast x (2M float4s); blocks [8192,12288) cast the
// 4 weight matrices (1024 blocks each). wq pre-scaled by 0.125 (exact pow-2).
__global__ __launch_bounds__(256) void cast_all(const float* __restrict__ x,
                                                const float* __restrict__ a, const float* __restrict__ b,
                                                const float* __restrict__ c, const float* __restrict__ d,
                                                unsigned short* __restrict__ xo,
                                                unsigned short* __restrict__ oa, unsigned short* __restrict__ ob,
                                                unsigned short* __restrict__ oc, unsigned short* __restrict__ od) {
  int blk = blockIdx.x;
  if (blk < 8192) {
    int i = blk * 256 + threadIdx.x;
    float4 v = reinterpret_cast<const float4*>(x)[i];
    ushort4 o;
    o.x = f2b(v.x); o.y = f2b(v.y); o.z = f2b(v.z); o.w = f2b(v.w);
    reinterpret_cast<ushort4*>(xo)[i] = o;
  } else {
    blk -= 8192;
    int which = blk >> 10;
    int i = (blk & 1023) * 256 + threadIdx.x;   // [0, 262144) float4s
    const float* s = (which == 0) ? a : (which == 1) ? b : (which == 2) ? c : d;
    unsigned short* o = (which == 0) ? oa : (which == 1) ? ob : (which == 2) ? oc : od;
    float sc = (which == 0) ? 0.125f : 1.0f;
    float4 v = reinterpret_cast<const float4*>(s)[i];
    ushort4 u;
    u.x = f2b(v.x * sc); u.y = f2b(v.y * sc); u.z = f2b(v.z * sc); u.w = f2b(v.w * sc);
    reinterpret_cast<ushort4*>(o)[i] = u;
  }
}

// ---------------- fused QKV GEMM: 3 modes per block, 128x128 tiles, BK=32 ----
// One block computes Q, K, V tiles for the same (mt,nt): A staged ONCE per
// K-step (was 3x), 48 MFMA per barrier (was 16) -> 1.5x arithmetic intensity
// per staged byte, 3x MFMA per barrier drain, A fetched from HBM once.
// acc[3][4][4] = 192 VGPR; __launch_bounds__(256,2) caps at 256 -> 2 blocks/CU
// (LDS 2 x 32KB buffers = 64KB/block also gives exactly 2).
__global__ __launch_bounds__(256, 2) void gemm_qkv(const unsigned short* __restrict__ A,
                                                   const unsigned short* __restrict__ Wq,
                                                   const unsigned short* __restrict__ Wk,
                                                   const unsigned short* __restrict__ Wv,
                                                   unsigned short* __restrict__ Qb,
                                                   unsigned short* __restrict__ Kb,
                                                   unsigned short* __restrict__ Vt) {
  __shared__ char smem[65536];   // 2 bufs x (A 8KB + Wq 8KB + Wk 8KB + Wv 8KB)
  int t = threadIdx.x;
  int lane = t & 63;
  int w = t >> 6;
  int l16 = lane & 15, q4 = lane >> 4;
  int mt = blockIdx.x >> 3, nt = blockIdx.x & 7;
  int m0 = mt * 128, n0 = nt * 128;
  int mw = (w & 1) * 64, nw = (w >> 1) * 64;

  const f32x4 zero4 = {0.f, 0.f, 0.f, 0.f};
  f32x4 acc[3][4][4];
#pragma unroll
  for (int md = 0; md < 3; ++md)
#pragma unroll
    for (int mi = 0; mi < 4; ++mi)
#pragma unroll
      for (int nj = 0; nj < 4; ++nj) acc[md][mi][nj] = zero4;

  // staging: thread t stages 32B of row rl0 (and rl0+64 via +64*DM) per tile.
  // swz(rl0+64) == swz(rl0) since 64+(64>>2) = 80 ≡ 0 (mod 4) -> one pointer
  // per stream. Source pre-swizzle = read-side chunk swizzle (same involution).
  int rl0 = t >> 2, cp = t & 3;
  int sw = ((cp - rl0 - (rl0 >> 2)) & 3) * 8;
  const unsigned short* ga = A  + (long)(m0 + rl0) * DM + sw;
  const unsigned short* gq = Wq + (long)(n0 + rl0) * DM + sw;
  const unsigned short* gk = Wk + (long)(n0 + rl0) * DM + sw;
  const unsigned short* gv = Wv + (long)(n0 + rl0) * DM + sw;
  char* ldst = smem + t * 16;

  // hoisted fragment LDS offsets (loop-invariant)
  int aoff[4], woff[4];
#pragma unroll
  for (int mi = 0; mi < 4; ++mi) {
    int r = mw + mi * 16 + l16;
    aoff[mi] = r * 32 + ((q4 + r + (r >> 2)) & 3) * 8;
  }
#pragma unroll
  for (int nj = 0; nj < 4; ++nj) {
    int r = nw + nj * 16 + l16;
    woff[nj] = r * 32 + ((q4 + r + (r >> 2)) & 3) * 8;
  }

  auto issue = [&](int bufB) {
    gl_lds16(ga,           ldst + bufB);
    gl_lds16(ga + 64 * DM, ldst + bufB + 4096);
    gl_lds16(gq,           ldst + bufB + 8192);
    gl_lds16(gq + 64 * DM, ldst + bufB + 12288);
    gl_lds16(gk,           ldst + bufB + 16384);
    gl_lds16(gk + 64 * DM, ldst + bufB + 20480);
    gl_lds16(gv,           ldst + bufB + 24576);
    gl_lds16(gv + 64 * DM, ldst + bufB + 28672);
    ga += 32; gq += 32; gk += 32; gv += 32;
  };

  issue(0);
  for (int ks = 0; ks < 32; ++ks) {
    __syncthreads();                        // buf[ks&1] staged; other buf free
    if (ks + 1 < 32) issue(((ks + 1) & 1) * 32768);

    const unsigned short* base = (const unsigned short*)(smem + (ks & 1) * 32768);
    short8 af[4];
#pragma unroll
    for (int mi = 0; mi < 4; ++mi) af[mi] = ldfrag_bf(base + aoff[mi]);
#pragma unroll
    for (int md = 0; md < 3; ++md) {
      const unsigned short* Wb = base + 4096 + md * 4096;   // ushort offsets
#pragma unroll
      for (int nj = 0; nj < 4; ++nj) {
        short8 wfj = ldfrag_bf(Wb + woff[nj]);
#pragma unroll
        for (int mi = 0; mi < 4; ++mi)
          acc[md][mi][nj] = __builtin_amdgcn_mfma_f32_16x16x32_bf16(af[mi], wfj, acc[md][mi][nj], 0, 0, 0);
      }
    }
  }

  // ---- epilogue: Q/K scatter (b,h wave-constant -> base + immediates) ----
  int b = m0 >> 11;
  int h = (n0 + nw) >> 6;
  long bh0 = (long)(b * NH + h);
  long obase = (bh0 * SEQ + (m0 & 2047) + mw + q4 * 4) * DKH + l16;
  {
    unsigned short* opq = Qb + obase;
    unsigned short* opk = Kb + obase;
#pragma unroll
    for (int mi = 0; mi < 4; ++mi)
#pragma unroll
      for (int nj = 0; nj < 4; ++nj)
#pragma unroll
        for (int r = 0; r < 4; ++r) {
          opq[mi * 1024 + r * 64 + nj * 16] = f2b(acc[0][mi][nj][r]);
          opk[mi * 1024 + r * 64 + nj * 16] = f2b(acc[1][mi][nj][r]);
        }
  }

  // ---- V^T via LDS: wave tile = 64 s-rows x 64 d-cols (exactly one head) ----
  __syncthreads();                       // everyone done reading K-loop LDS
  unsigned short* vle = (unsigned short*)(smem + w * 8192);   // 64x64 ushorts
  unsigned int* vle32 = (unsigned int*)vle;
#pragma unroll
  for (int nj = 0; nj < 4; ++nj) {
    int d = nj * 16 + l16;
    int k8 = (d & 7) * 8;
#pragma unroll
    for (int mi = 0; mi < 4; ++mi)
#pragma unroll
      for (int r = 0; r < 4; r += 2) {
        int s = mi * 16 + q4 * 4 + r;
        unsigned int pk = (unsigned int)f2b(acc[2][mi][nj][r]) |
                          ((unsigned int)f2b(acc[2][mi][nj][r + 1]) << 16);
        vle32[d * 32 + ((s ^ k8) >> 1)] = pk;   // XOR chunk swizzle
      }
  }
  __asm__ volatile("s_waitcnt lgkmcnt(0)" ::: "memory");  // wave-local round-trip
  {
    int sbase = (m0 + mw) & 2047;          // within-batch seq index
    int dr_lo = lane >> 3, c = lane & 7;
    // (dr & 7) == dr_lo for every pass -> read offset is pass-invariant + imm
    const unsigned short* vr = vle + dr_lo * 64 + (c ^ dr_lo) * 8;
    unsigned short* vtp = Vt + (bh0 * DKH + dr_lo) * SEQ + sbase + c * 8;
#pragma unroll
    for (int pass = 0; pass < 8; ++pass) {
      short8 vv = ldfrag_bf(vr + pass * 512);
      *reinterpret_cast<short8*>(vtp + (long)pass * 8 * SEQ) = vv;
    }
  }
}

// ---------------- O-projection GEMM, depth-2 prefetch, 3-buffer -------------
__global__ __launch_bounds__(256) void gemm_o(const unsigned short* __restrict__ A,
                                              const unsigned short* __restrict__ W,
                                              float* __restrict__ outp) {
  __shared__ char smem[49152];
  unsigned short* At = (unsigned short*)smem;
  unsigned short* Wt = (unsigned short*)(smem + 24576);
  int t = threadIdx.x;
  int lane = t & 63;
  int w = t >> 6;
  int l16 = lane & 15, q4 = lane >> 4;
  // bijective XCD swizzle: 512 blocks = 8 XCDs x 64
  int swz = (blockIdx.x & 7) * 64 + (blockIdx.x >> 3);
  int mt = swz >> 3, nt = swz & 7;
  int m0 = mt * 128, n0 = nt * 128;
  int mw = (w & 1) * 64, nw = (w >> 1) * 64;

  const f32x4 zero4 = {0.f, 0.f, 0.f, 0.f};
  f32x4 acc[4][4];
#pragma unroll
  for (int mi = 0; mi < 4; ++mi)
#pragma unroll
    for (int nj = 0; nj < 4; ++nj) acc[mi][nj] = zero4;

  int rl0 = t >> 2, cp = t & 3;
  int rl1 = rl0 + 64;
  int sw0 = ((cp - rl0 - (rl0 >> 2)) & 3) * 8;
  int sw1 = ((cp - rl1 - (rl1 >> 2)) & 3) * 8;
  // A is [B,H,S,dk] head-chunked: k advances 32 within a head, then hops heads
  int b0 = m0 >> 11;
  const unsigned short* ga0;
  const unsigned short* ga1;
  {
    int s0 = (m0 & 2047) + rl0;
    ga0 = A + (long)b0 * (NH * SEQ * DKH) + (long)s0 * DKH + sw0;
    int s1 = (m0 & 2047) + rl1;
    ga1 = A + (long)b0 * (NH * SEQ * DKH) + (long)s1 * DKH + sw1;
  }
  const unsigned short* gw0 = W + (long)(n0 + rl0) * DM + sw0;
  const unsigned short* gw1 = W + (long)(n0 + rl1) * DM + sw1;
  char* lA = (char*)At + t * 16;
  char* lW = (char*)Wt + t * 16;

  int aoff[4], woff[4];
#pragma unroll
  for (int mi = 0; mi < 4; ++mi) {
    int r = mw + mi * 16 + l16;
    aoff[mi] = r * 32 + ((q4 + r + (r >> 2)) & 3) * 8;
  }
#pragma unroll
  for (int nj = 0; nj < 4; ++nj) {
    int r = nw + nj * 16 + l16;
    woff[nj] = r * 32 + ((q4 + r + (r >> 2)) & 3) * 8;
  }

  int js = 0;                                 // next step index to issue
  auto issue = [&](int boB) {
    gl_lds16(ga0, lA + boB); gl_lds16(ga1, lA + boB + 4096);
    gl_lds16(gw0, lW + boB); gl_lds16(gw1, lW + boB + 4096);
    int adv = ((js & 1) == 0) ? 32 : (SEQ * DKH - 32);   // head-hop on odd js
    ga0 += adv; ga1 += adv; gw0 += 32; gw1 += 32;
    ++js;
  };

  issue(0);
  issue(8192);
  __asm__ volatile("s_waitcnt vmcnt(4)" ::: "memory");
  __builtin_amdgcn_sched_barrier(0);
  __builtin_amdgcn_s_barrier();
  __builtin_amdgcn_sched_barrier(0);

  int cbB = 0, pbB = 16384;
  for (int ks = 0; ks < 32; ++ks) {
    if (ks < 30) issue(pbB);

    const unsigned short* Ab = (const unsigned short*)((char*)At + cbB);
    const unsigned short* Wb = (const unsigned short*)((char*)Wt + cbB);
    short8 af[4], wf[4];
#pragma unroll
    for (int mi = 0; mi < 4; ++mi) af[mi] = ldfrag_bf(Ab + aoff[mi]);
#pragma unroll
    for (int nj = 0; nj < 4; ++nj) wf[nj] = ldfrag_bf(Wb + woff[nj]);
#pragma unroll
    for (int mi = 0; mi < 4; ++mi)
#pragma unroll
      for (int nj = 0; nj < 4; ++nj)
        acc[mi][nj] = __builtin_amdgcn_mfma_f32_16x16x32_bf16(af[mi], wf[nj], acc[mi][nj], 0, 0, 0);

    if (ks < 31) {
      if (ks < 30) { __asm__ volatile("s_waitcnt vmcnt(4)" ::: "memory"); }
      else         { __asm__ volatile("s_waitcnt vmcnt(0)" ::: "memory"); }
      __builtin_amdgcn_sched_barrier(0);
      __builtin_amdgcn_s_barrier();
      __builtin_amdgcn_sched_barrier(0);
    }
    cbB += 8192; if (cbB == 24576) cbB = 0;
    pbB += 8192; if (pbB == 24576) pbB = 0;
  }

  // hoisted epilogue: one base, compile-time offsets
  {
    float* op = outp + (long)(m0 + mw + q4 * 4) * DM + n0 + nw + l16;
#pragma unroll
    for (int mi = 0; mi < 4; ++mi)
#pragma unroll
      for (int nj = 0; nj < 4; ++nj)
#pragma unroll
        for (int r = 0; r < 4; ++r)
          op[(mi * 16 + r) * DM + nj * 16] = acc[mi][nj][r];
  }
}

// ---------------- slow GEMM (direct-global, fp32 cvt) — small-ws fallback ----
template<int MODE, bool AF32, bool WF32>
__global__ __launch_bounds__(256) void gemm_s(const void* __restrict__ Ap,
                                              const void* __restrict__ Wp,
                                              void* __restrict__ outp) {
  int wid  = (blockIdx.x * 256 + threadIdx.x) >> 6;
  int lane = threadIdx.x & 63;
  int l16  = lane & 15, q4 = lane >> 4;
  int tn = wid & 15, tm = wid >> 4;
  int m0 = tm * 32, n0 = tn * 64;

  const float*          Af = (const float*)Ap;
  const unsigned short* Ab = (const unsigned short*)Ap;
  const float*          Wf = (const float*)Wp;
  const unsigned short* Wb = (const unsigned short*)Wp;

  const f32x4 zero4 = {0.f, 0.f, 0.f, 0.f};
  f32x4 acc[2][4];
#pragma unroll
  for (int mi = 0; mi < 2; ++mi)
#pragma unroll
    for (int j = 0; j < 4; ++j) acc[mi][j] = zero4;

  int wrow[4];
#pragma unroll
  for (int j = 0; j < 4; ++j) wrow[j] = (n0 + j * 16 + l16) * DM;
  int arow[2] = {0, 0};
  long abase[2] = {0, 0};
  if (MODE != 3) {
#pragma unroll
    for (int mi = 0; mi < 2; ++mi) arow[mi] = (m0 + mi * 16 + l16) * DM;
  } else {
    int b = m0 >> 11;
#pragma unroll
    for (int mi = 0; mi < 2; ++mi) {
      int srow = (m0 & 2047) + mi * 16 + l16;
      abase[mi] = (long)b * (NH * SEQ * DKH) + (long)srow * DKH;
    }
  }

#pragma unroll 2
  for (int ks = 0; ks < 32; ++ks) {
    int ko = ks * 32 + q4 * 8;
    short8 bfrag[4];
#pragma unroll
    for (int j = 0; j < 4; ++j) {
      if constexpr (WF32) bfrag[j] = ldfrag_f32(Wf + wrow[j] + ko);
      else                bfrag[j] = ldfrag_bf(Wb + wrow[j] + ko);
    }
    short8 afrag[2];
    if constexpr (MODE != 3) {
#pragma unroll
      for (int mi = 0; mi < 2; ++mi) {
        if constexpr (AF32) afrag[mi] = ldfrag_f32(Af + arow[mi] + ko);
        else                afrag[mi] = ldfrag_bf(Ab + arow[mi] + ko);
      }
    } else {
      int h = ko >> 6, e63 = ko & 63;
#pragma unroll
      for (int mi = 0; mi < 2; ++mi)
        afrag[mi] = ldfrag_bf(Ab + abase[mi] + (long)h * (SEQ * DKH) + e63);
    }
#pragma unroll
    for (int mi = 0; mi < 2; ++mi)
#pragma unroll
      for (int j = 0; j < 4; ++j)
        acc[mi][j] = __builtin_amdgcn_mfma_f32_16x16x32_bf16(afrag[mi], bfrag[j], acc[mi][j], 0, 0, 0);
  }

#pragma unroll
  for (int mi = 0; mi < 2; ++mi) {
#pragma unroll
    for (int j = 0; j < 4; ++j) {
#pragma unroll
      for (int r = 0; r < 4; ++r) {
        float v = acc[mi][j][r];
        int m = m0 + mi * 16 + q4 * 4 + r;
        int n = n0 + j * 16 + l16;
        if constexpr (MODE == 3) {
          reinterpret_cast<float*>(outp)[(long)m * DM + n] = v;
        } else {
          int b = m >> 11, s = m & 2047;
          int h = n >> 6, d = n & 63;
          long bh = (long)(b * NH + h);
          unsigned short* o = reinterpret_cast<unsigned short*>(outp);
          if constexpr (MODE == 0)      o[(bh * SEQ + s) * DKH + d] = f2b(v * 0.125f);
          else if constexpr (MODE == 1) o[(bh * SEQ + s) * DKH + d] = f2b(v);
          else                          o[(bh * DKH + d) * SEQ + s] = f2b(v);
        }
      }
    }
  }
}

// ---------------- workgroup-tiled flash attention, 32x32 MFMA, in-reg softmax
// Swapped QK^T (mfma(K,Q)) keeps the whole softmax row in registers; exp ->
// chop-to-bf16 -> pack -> permlane32_swap feeds PV A-frags directly (T12).
__global__ __launch_bounds__(256, 4) void attn_k(const unsigned short* __restrict__ Kbuf,
                                                 const unsigned short* __restrict__ Vt,
                                                 const unsigned short* __restrict__ Qbuf,
                                                 unsigned short* __restrict__ Obuf) {
  __shared__ unsigned short Kt[2][64 * 64];    // 16 KB, double-buffered K tile
  __shared__ unsigned short Vts[2][64 * 64];   // 16 KB, double-buffered V^T tile

  int t = threadIdx.x;
  int lane = t & 63;
  int w = t >> 6;
  int l31 = lane & 31, hi = lane >> 5;
  int qb = 15 - (blockIdx.x >> 6);             // heavy blocks first
  int bh = blockIdx.x & 63;
  int q0 = qb * 128;
  int qw0 = q0 + w * 32;                       // this wave's 32 q-rows

  const unsigned short* Qh = Qbuf + (long)bh * (SEQ * DKH);
  const unsigned short* Kh = Kbuf + (long)bh * (SEQ * DKH);
  const unsigned short* Vh = Vt   + (long)bh * (DKH * SEQ);

  // Q as B-fragment for swapped QK^T: lane holds Q[q=l31][d = dt*16 + hi*8 + j]
  short8 qf[4];
#pragma unroll
  for (int dt = 0; dt < 4; ++dt)
    qf[dt] = ldfrag_bf(Qh + (long)(qw0 + l31) * DKH + dt * 16 + hi * 8);

  f32x16 om[2];                                // O accum: row=q (crow), col=d
#pragma unroll
  for (int dv = 0; dv < 2; ++dv)
#pragma unroll
    for (int r = 0; r < 16; ++r) om[dv][r] = 0.f;
  float lsum = 0.f;                            // per-lane partial row-sum (q=l31)

  // K A-frag: row kr = sub*32+l31, d-chunk8 = dt*2+hi, XOR-swizzled slot
  int koff[2][4];
#pragma unroll
  for (int sub = 0; sub < 2; ++sub) {
    int kr = sub * 32 + l31;
#pragma unroll
    for (int dt = 0; dt < 4; ++dt)
      koff[sub][dt] = kr * 64 + ((dt * 2 + hi + kr + (kr >> 3)) & 7) * 8;
  }
  // V B-frag: row dr = dv*32+l31, k-chunk8 = kc*2+hi
  int voff[2][4];
#pragma unroll
  for (int dv = 0; dv < 2; ++dv) {
    int dr = dv * 32 + l31;
#pragma unroll
    for (int kc = 0; kc < 4; ++kc)
      voff[dv][kc] = dr * 64 + ((kc * 2 + hi + dr + (dr >> 3)) & 7) * 8;
  }

  // staging pointers (pre-swizzled global source, linear LDS dest)
  int rl0 = t >> 3, cp = t & 7;
  int rl1 = rl0 + 32;
  int sw0 = ((cp - rl0 - (rl0 >> 3)) & 7) * 8;
  int sw1 = ((cp - rl1 - (rl1 >> 3)) & 7) * 8;
  const unsigned short* kp0 = Kh + (long)rl0 * DKH + sw0;
  const unsigned short* kp1 = Kh + (long)rl1 * DKH + sw1;
  const unsigned short* vp0 = Vh + (long)rl0 * SEQ + sw0;
  const unsigned short* vp1 = Vh + (long)rl1 * SEQ + sw1;
  char* lK = (char*)Kt + t * 16;
  char* lV = (char*)Vts + t * 16;

  int nk = 2 * qb + 2;                         // 64-key tiles needed
  gl_lds16(kp0, lK); gl_lds16(kp1, lK + 4096);
  gl_lds16(vp0, lV); gl_lds16(vp1, lV + 4096);

  for (int it = 0; it < nk; ++it) {
    __syncthreads();                           // tile it staged
    if (it + 1 < nk) {
      kp0 += 64 * DKH; kp1 += 64 * DKH; vp0 += 64; vp1 += 64;
      int bo = ((it + 1) & 1) * 8192;
      gl_lds16(kp0, lK + bo); gl_lds16(kp1, lK + bo + 4096);
      gl_lds16(vp0, lV + bo); gl_lds16(vp1, lV + bo + 4096);
    }

    int k0 = it * 64;
    if (k0 <= qw0 + 31) {                      // wave-uniform causal activity
      const unsigned short* KT = Kt[0] + (it & 1) * 4096;
      const unsigned short* VT = Vts[0] + (it & 1) * 4096;

#pragma unroll
      for (int sub = 0; sub < 2; ++sub) {
        int ksb = k0 + sub * 32;
        if (ksb <= qw0 + 31) {                 // 32-key sub-tile active (uniform)
          // ---- swapped QK^T: S[k][q], col=q=l31, row=k=crow(r,hi)+ksb ----
          f32x16 s;
#pragma unroll
          for (int r = 0; r < 16; ++r) s[r] = 0.f;
#pragma unroll
          for (int dt = 0; dt < 4; ++dt) {
            short8 kf = ldfrag_bf(KT + koff[sub][dt]);
            s = __builtin_amdgcn_mfma_f32_32x32x16_bf16(kf, qf[dt], s, 0, 0, 0);
          }

          // ---- exp, causal mask, chop to bf16, pack k-pairs ----
          bool needmask = (ksb + 31 > qw0);
          int qr = qw0 + l31;
          unsigned int pk[4][2];               // [m][p]: k = 8m+4hi+2p+{0,1}
#pragma unroll
          for (int r = 0; r < 16; r += 2) {
            float p0 = __expf(s[r]);
            float p1 = __expf(s[r + 1]);
            if (needmask) {
              int key = ksb + (r & 3) + 8 * (r >> 2) + 4 * hi;
              p0 = (key <= qr) ? p0 : 0.f;
              p1 = (key + 1 <= qr) ? p1 : 0.f;
            }
            unsigned int u0 = __float_as_uint(p0) & 0xffff0000u;
            unsigned int u1 = __float_as_uint(p1) & 0xffff0000u;
            lsum += __uint_as_float(u0) + __uint_as_float(u1);  // sums the SAME
            pk[r >> 2][(r >> 1) & 1] = (u0 >> 16) | u1;         // chopped values
          }

          // ---- redistribute into PV A-frags: one swap fills two words ----
#pragma unroll
          for (int c = 0; c < 2; ++c) {
            u32x2 r0 = __builtin_amdgcn_permlane32_swap(pk[2 * c][0], pk[2 * c + 1][0], false, false);
            u32x2 r1 = __builtin_amdgcn_permlane32_swap(pk[2 * c][1], pk[2 * c + 1][1], false, false);
            u32x4 pw;
            pw.x = r0.x; pw.y = r1.x; pw.z = r0.y; pw.w = r1.y;
            short8 pa = __builtin_bit_cast(short8, pw);  // P[q=l31][k'=8hi+j]
            int kc = sub * 2 + c;
#pragma unroll
            for (int dv = 0; dv < 2; ++dv) {
              short8 vf = ldfrag_bf(VT + voff[dv][kc]);
              om[dv] = __builtin_amdgcn_mfma_f32_32x32x16_bf16(pa, vf, om[dv], 0, 0, 0);
            }
          }
        }
      }
    }
  }

  // ---- normalize: partner-sum lsum (lane l <-> l+32 share q=l31) ----
  u32x2 lz = __builtin_amdgcn_permlane32_swap(__float_as_uint(lsum), __float_as_uint(lsum),
                                              false, false);
  float inv = 1.f / (__uint_as_float(lz.x) + __uint_as_float(lz.y));  // for q=l31

  long obase = (long)bh * (SEQ * DKH);
#pragma unroll
  for (int r = 0; r < 16; ++r) {
    int qrow = (r & 3) + 8 * (r >> 2) + 4 * hi;   // om row -> q
    float invq = __shfl(inv, qrow);               // inv for that q lives at lane qrow
    long rowb = obase + (long)(qw0 + qrow) * DKH + l31;
    Obuf[rowb]      = f2b(om[0][r] * invq);
    Obuf[rowb + 32] = f2b(om[1][r] * invq);
  }
}

extern "C" void kernel_launch(void* const* d_in, const int* in_sizes, int n_in,
                              void* d_out, int out_size, void* d_ws, size_t ws_size,
                              hipStream_t stream) {
  const float* x  = (const float*)d_in[0];
  const float* wq = (const float*)d_in[1];
  const float* wk = (const float*)d_in[2];
  const float* wv = (const float*)d_in[3];
  const float* wo = (const float*)d_in[4];

  // Q/K bf16 staged in d_out (exactly 16M ushorts); final GEMM overwrites with fp32.
  unsigned short* Qb = (unsigned short*)d_out;
  unsigned short* Kb = Qb + 8388608;

  if (ws_size >= 41943040ull) {
    // ---- fast path (>=40 MiB ws): xb 16 MiB | weights 8 MiB | Vt 16 MiB ----
    unsigned short* xb  = (unsigned short*)d_ws;   // becomes O after projections
    unsigned short* wqb = xb + 8388608;
    unsigned short* wkb = wqb + 1048576;
    unsigned short* wvb = wkb + 1048576;
    unsigned short* wob = wvb + 1048576;
    unsigned short* Vt  = wob + 1048576;           // [B,H,dk,S]
    unsigned short* Ob  = xb;

    cast_all<<<12288, 256, 0, stream>>>(x, wq, wk, wv, wo, xb, wqb, wkb, wvb, wob);

    gemm_qkv<<<512, 256, 0, stream>>>(xb, wqb, wkb, wvb, Qb, Kb, Vt);
    attn_k<<<1024, 256, 0, stream>>>(Kb, Vt, Qb, Ob);
    gemm_o<<<512, 256, 0, stream>>>(Ob, wob, (float*)d_out);
  } else if (ws_size >= 33554432ull) {
    // ---- minimal path (32 MiB ws): fp32 direct gemms, fast attention ----
    unsigned short* Vt = (unsigned short*)d_ws;   // 8M els [B,H,dk,S]
    unsigned short* Ob = Vt + 8388608;            // 8M els [B,H,S,dk]

    gemm_s<0, true, true><<<1024, 256, 0, stream>>>(x, wq, Qb);
    gemm_s<1, true, true><<<1024, 256, 0, stream>>>(x, wk, Kb);
    gemm_s<2, true, true><<<1024, 256, 0, stream>>>(x, wv, Vt);
    attn_k<<<1024, 256, 0, stream>>>(Kb, Vt, Qb, Ob);
    gemm_s<3, false, true><<<1024, 256, 0, stream>>>(Ob, wo, d_out);
  } else {
    zero_f32<<<8192, 256, 0, stream>>>((float*)d_out, 2097152);
  }
}

// Round 6
// 232.082 us; speedup vs baseline: 1.0858x; 1.0037x over previous
//
#include <hip/hip_runtime.h>

#define SEQ 2048
#define DM 1024
#define NH 16
#define DKH 64
// M rows total = 4*2048 = 8192

typedef __attribute__((ext_vector_type(8))) short short8;   // 8 bf16
typedef __attribute__((ext_vector_type(4))) float f32x4;
typedef __attribute__((ext_vector_type(2))) float f32x2;
typedef __attribute__((ext_vector_type(16))) float f32x16;
typedef __attribute__((ext_vector_type(2))) unsigned int u32x2;
typedef __attribute__((ext_vector_type(4))) unsigned int u32x4;

static __device__ __forceinline__ unsigned short f2b(float f) {
  unsigned int u = __float_as_uint(f);
  u += 0x7fffu + ((u >> 16) & 1u);   // round-to-nearest-even
  return (unsigned short)(u >> 16);
}

static __device__ __forceinline__ short8 ldfrag_bf(const unsigned short* p) {
  return *reinterpret_cast<const short8*>(p);
}
static __device__ __forceinline__ short8 ldfrag_f32(const float* p) {
  const float4* q = reinterpret_cast<const float4*>(p);
  float4 a = q[0], b = q[1];
  short8 r;
  r[0] = (short)f2b(a.x); r[1] = (short)f2b(a.y);
  r[2] = (short)f2b(a.z); r[3] = (short)f2b(a.w);
  r[4] = (short)f2b(b.x); r[5] = (short)f2b(b.y);
  r[6] = (short)f2b(b.z); r[7] = (short)f2b(b.w);
  return r;
}

// async global->LDS, 16 B per lane. LDS side MUST be wave-uniform base + lane*16.
static __device__ __forceinline__ void gl_lds16(const void* g, void* l) {
  __builtin_amdgcn_global_load_lds(
      (const __attribute__((address_space(1))) unsigned int*)g,
      (__attribute__((address_space(3))) unsigned int*)l, 16, 0, 0);
}

__global__ __launch_bounds__(256) void zero_f32(float* __restrict__ p, int n4) {
  int i = blockIdx.x * 256 + threadIdx.x;
  if (i < n4) {
    float4 z = {0.f, 0.f, 0.f, 0.f};
    reinterpret_cast<float4*>(p)[i] = z;
  }
}

// fused cast: blocks [0,8192) cast x (2M float4s); blocks [8192,12288) cast the
// 4 weight matrices (1024 blocks each). wq pre-scaled by 0.125 (exact pow-2).
__global__ __launch_bounds__(256) void cast_all(const float* __restrict__ x,
                                                const float* __restrict__ a, const float* __restrict__ b,
                                                const float* __restrict__ c, const float* __restrict__ d,
                                                unsigned short* __restrict__ xo,
                                                unsigned short* __restrict__ oa, unsigned short* __restrict__ ob,
                                                unsigned short* __restrict__ oc, unsigned short* __restrict__ od) {
  int blk = blockIdx.x;
  if (blk < 8192) {
    int i = blk * 256 + threadIdx.x;
    float4 v = reinterpret_cast<const float4*>(x)[i];
    ushort4 o;
    o.x = f2b(v.x); o.y = f2b(v.y); o.z = f2b(v.z); o.w = f2b(v.w);
    reinterpret_cast<ushort4*>(xo)[i] = o;
  } else {
    blk -= 8192;
    int which = blk >> 10;
    int i = (blk & 1023) * 256 + threadIdx.x;   // [0, 262144) float4s
    const float* s = (which == 0) ? a : (which == 1) ? b : (which == 2) ? c : d;
    unsigned short* o = (which == 0) ? oa : (which == 1) ? ob : (which == 2) ? oc : od;
    float sc = (which == 0) ? 0.125f : 1.0f;
    float4 v = reinterpret_cast<const float4*>(s)[i];
    ushort4 u;
    u.x = f2b(v.x * sc); u.y = f2b(v.y * sc); u.z = f2b(v.z * sc); u.w = f2b(v.w * sc);
    reinterpret_cast<ushort4*>(o)[i] = u;
  }
}

// ---------------- fused QKV GEMM: 3 modes per block, 128x128 tiles, BK=32 ----
// One block computes Q, K, V tiles for the same (mt,nt): A staged ONCE per
// K-step, 48 MFMA per barrier, A fetched from HBM once.
__global__ __launch_bounds__(256, 2) void gemm_qkv(const unsigned short* __restrict__ A,
                                                   const unsigned short* __restrict__ Wq,
                                                   const unsigned short* __restrict__ Wk,
                                                   const unsigned short* __restrict__ Wv,
                                                   unsigned short* __restrict__ Qb,
                                                   unsigned short* __restrict__ Kb,
                                                   unsigned short* __restrict__ Vt) {
  __shared__ char smem[65536];   // 2 bufs x (A 8KB + Wq 8KB + Wk 8KB + Wv 8KB)
  int t = threadIdx.x;
  int lane = t & 63;
  int w = t >> 6;
  int l16 = lane & 15, q4 = lane >> 4;
  int mt = blockIdx.x >> 3, nt = blockIdx.x & 7;
  int m0 = mt * 128, n0 = nt * 128;
  int mw = (w & 1) * 64, nw = (w >> 1) * 64;

  const f32x4 zero4 = {0.f, 0.f, 0.f, 0.f};
  f32x4 acc[3][4][4];
#pragma unroll
  for (int md = 0; md < 3; ++md)
#pragma unroll
    for (int mi = 0; mi < 4; ++mi)
#pragma unroll
      for (int nj = 0; nj < 4; ++nj) acc[md][mi][nj] = zero4;

  // staging: thread t stages 32B of row rl0 (and rl0+64 via +64*DM) per tile.
  // swz(rl0+64) == swz(rl0) since 64+(64>>2) = 80 ≡ 0 (mod 4) -> one pointer
  // per stream. Source pre-swizzle = read-side chunk swizzle (same involution).
  int rl0 = t >> 2, cp = t & 3;
  int sw = ((cp - rl0 - (rl0 >> 2)) & 3) * 8;
  const unsigned short* ga = A  + (long)(m0 + rl0) * DM + sw;
  const unsigned short* gq = Wq + (long)(n0 + rl0) * DM + sw;
  const unsigned short* gk = Wk + (long)(n0 + rl0) * DM + sw;
  const unsigned short* gv = Wv + (long)(n0 + rl0) * DM + sw;
  char* ldst = smem + t * 16;

  // hoisted fragment LDS offsets (loop-invariant)
  int aoff[4], woff[4];
#pragma unroll
  for (int mi = 0; mi < 4; ++mi) {
    int r = mw + mi * 16 + l16;
    aoff[mi] = r * 32 + ((q4 + r + (r >> 2)) & 3) * 8;
  }
#pragma unroll
  for (int nj = 0; nj < 4; ++nj) {
    int r = nw + nj * 16 + l16;
    woff[nj] = r * 32 + ((q4 + r + (r >> 2)) & 3) * 8;
  }

  auto issue = [&](int bufB) {
    gl_lds16(ga,           ldst + bufB);
    gl_lds16(ga + 64 * DM, ldst + bufB + 4096);
    gl_lds16(gq,           ldst + bufB + 8192);
    gl_lds16(gq + 64 * DM, ldst + bufB + 12288);
    gl_lds16(gk,           ldst + bufB + 16384);
    gl_lds16(gk + 64 * DM, ldst + bufB + 20480);
    gl_lds16(gv,           ldst + bufB + 24576);
    gl_lds16(gv + 64 * DM, ldst + bufB + 28672);
    ga += 32; gq += 32; gk += 32; gv += 32;
  };

  issue(0);
  for (int ks = 0; ks < 32; ++ks) {
    __syncthreads();                        // buf[ks&1] staged; other buf free
    if (ks + 1 < 32) issue(((ks + 1) & 1) * 32768);

    const unsigned short* base = (const unsigned short*)(smem + (ks & 1) * 32768);
    short8 af[4];
#pragma unroll
    for (int mi = 0; mi < 4; ++mi) af[mi] = ldfrag_bf(base + aoff[mi]);
#pragma unroll
    for (int md = 0; md < 3; ++md) {
      const unsigned short* Wb = base + 4096 + md * 4096;   // ushort offsets
#pragma unroll
      for (int nj = 0; nj < 4; ++nj) {
        short8 wfj = ldfrag_bf(Wb + woff[nj]);
#pragma unroll
        for (int mi = 0; mi < 4; ++mi)
          acc[md][mi][nj] = __builtin_amdgcn_mfma_f32_16x16x32_bf16(af[mi], wfj, acc[md][mi][nj], 0, 0, 0);
      }
    }
  }

  // ---- epilogue: Q/K scatter (b,h wave-constant -> base + immediates) ----
  int b = m0 >> 11;
  int h = (n0 + nw) >> 6;
  long bh0 = (long)(b * NH + h);
  long obase = (bh0 * SEQ + (m0 & 2047) + mw + q4 * 4) * DKH + l16;
  {
    unsigned short* opq = Qb + obase;
    unsigned short* opk = Kb + obase;
#pragma unroll
    for (int mi = 0; mi < 4; ++mi)
#pragma unroll
      for (int nj = 0; nj < 4; ++nj)
#pragma unroll
        for (int r = 0; r < 4; ++r) {
          opq[mi * 1024 + r * 64 + nj * 16] = f2b(acc[0][mi][nj][r]);
          opk[mi * 1024 + r * 64 + nj * 16] = f2b(acc[1][mi][nj][r]);
        }
  }

  // ---- V^T via LDS: wave tile = 64 s-rows x 64 d-cols (exactly one head) ----
  __syncthreads();                       // everyone done reading K-loop LDS
  unsigned short* vle = (unsigned short*)(smem + w * 8192);   // 64x64 ushorts
  unsigned int* vle32 = (unsigned int*)vle;
#pragma unroll
  for (int nj = 0; nj < 4; ++nj) {
    int d = nj * 16 + l16;
    int k8 = (d & 7) * 8;
#pragma unroll
    for (int mi = 0; mi < 4; ++mi)
#pragma unroll
      for (int r = 0; r < 4; r += 2) {
        int s = mi * 16 + q4 * 4 + r;
        unsigned int pk = (unsigned int)f2b(acc[2][mi][nj][r]) |
                          ((unsigned int)f2b(acc[2][mi][nj][r + 1]) << 16);
        vle32[d * 32 + ((s ^ k8) >> 1)] = pk;   // XOR chunk swizzle
      }
  }
  __asm__ volatile("s_waitcnt lgkmcnt(0)" ::: "memory");  // wave-local round-trip
  {
    int sbase = (m0 + mw) & 2047;          // within-batch seq index
    int dr_lo = lane >> 3, c = lane & 7;
    // (dr & 7) == dr_lo for every pass -> read offset is pass-invariant + imm
    const unsigned short* vr = vle + dr_lo * 64 + (c ^ dr_lo) * 8;
    unsigned short* vtp = Vt + (bh0 * DKH + dr_lo) * SEQ + sbase + c * 8;
#pragma unroll
    for (int pass = 0; pass < 8; ++pass) {
      short8 vv = ldfrag_bf(vr + pass * 512);
      *reinterpret_cast<short8*>(vtp + (long)pass * 8 * SEQ) = vv;
    }
  }
}

// ---------------- O-projection GEMM, depth-2 prefetch, 3-buffer -------------
__global__ __launch_bounds__(256) void gemm_o(const unsigned short* __restrict__ A,
                                              const unsigned short* __restrict__ W,
                                              float* __restrict__ outp) {
  __shared__ char smem[49152];
  unsigned short* At = (unsigned short*)smem;
  unsigned short* Wt = (unsigned short*)(smem + 24576);
  int t = threadIdx.x;
  int lane = t & 63;
  int w = t >> 6;
  int l16 = lane & 15, q4 = lane >> 4;
  // bijective XCD swizzle: 512 blocks = 8 XCDs x 64
  int swz = (blockIdx.x & 7) * 64 + (blockIdx.x >> 3);
  int mt = swz >> 3, nt = swz & 7;
  int m0 = mt * 128, n0 = nt * 128;
  int mw = (w & 1) * 64, nw = (w >> 1) * 64;

  const f32x4 zero4 = {0.f, 0.f, 0.f, 0.f};
  f32x4 acc[4][4];
#pragma unroll
  for (int mi = 0; mi < 4; ++mi)
#pragma unroll
    for (int nj = 0; nj < 4; ++nj) acc[mi][nj] = zero4;

  int rl0 = t >> 2, cp = t & 3;
  int rl1 = rl0 + 64;
  int sw0 = ((cp - rl0 - (rl0 >> 2)) & 3) * 8;
  int sw1 = ((cp - rl1 - (rl1 >> 2)) & 3) * 8;
  // A is [B,H,S,dk] head-chunked: k advances 32 within a head, then hops heads
  int b0 = m0 >> 11;
  const unsigned short* ga0;
  const unsigned short* ga1;
  {
    int s0 = (m0 & 2047) + rl0;
    ga0 = A + (long)b0 * (NH * SEQ * DKH) + (long)s0 * DKH + sw0;
    int s1 = (m0 & 2047) + rl1;
    ga1 = A + (long)b0 * (NH * SEQ * DKH) + (long)s1 * DKH + sw1;
  }
  const unsigned short* gw0 = W + (long)(n0 + rl0) * DM + sw0;
  const unsigned short* gw1 = W + (long)(n0 + rl1) * DM + sw1;
  char* lA = (char*)At + t * 16;
  char* lW = (char*)Wt + t * 16;

  int aoff[4], woff[4];
#pragma unroll
  for (int mi = 0; mi < 4; ++mi) {
    int r = mw + mi * 16 + l16;
    aoff[mi] = r * 32 + ((q4 + r + (r >> 2)) & 3) * 8;
  }
#pragma unroll
  for (int nj = 0; nj < 4; ++nj) {
    int r = nw + nj * 16 + l16;
    woff[nj] = r * 32 + ((q4 + r + (r >> 2)) & 3) * 8;
  }

  int js = 0;                                 // next step index to issue
  auto issue = [&](int boB) {
    gl_lds16(ga0, lA + boB); gl_lds16(ga1, lA + boB + 4096);
    gl_lds16(gw0, lW + boB); gl_lds16(gw1, lW + boB + 4096);
    int adv = ((js & 1) == 0) ? 32 : (SEQ * DKH - 32);   // head-hop on odd js
    ga0 += adv; ga1 += adv; gw0 += 32; gw1 += 32;
    ++js;
  };

  issue(0);
  issue(8192);
  __asm__ volatile("s_waitcnt vmcnt(4)" ::: "memory");
  __builtin_amdgcn_sched_barrier(0);
  __builtin_amdgcn_s_barrier();
  __builtin_amdgcn_sched_barrier(0);

  int cbB = 0, pbB = 16384;
  for (int ks = 0; ks < 32; ++ks) {
    if (ks < 30) issue(pbB);

    const unsigned short* Ab = (const unsigned short*)((char*)At + cbB);
    const unsigned short* Wb = (const unsigned short*)((char*)Wt + cbB);
    short8 af[4], wf[4];
#pragma unroll
    for (int mi = 0; mi < 4; ++mi) af[mi] = ldfrag_bf(Ab + aoff[mi]);
#pragma unroll
    for (int nj = 0; nj < 4; ++nj) wf[nj] = ldfrag_bf(Wb + woff[nj]);
#pragma unroll
    for (int mi = 0; mi < 4; ++mi)
#pragma unroll
      for (int nj = 0; nj < 4; ++nj)
        acc[mi][nj] = __builtin_amdgcn_mfma_f32_16x16x32_bf16(af[mi], wf[nj], acc[mi][nj], 0, 0, 0);

    if (ks < 31) {
      if (ks < 30) { __asm__ volatile("s_waitcnt vmcnt(4)" ::: "memory"); }
      else         { __asm__ volatile("s_waitcnt vmcnt(0)" ::: "memory"); }
      __builtin_amdgcn_sched_barrier(0);
      __builtin_amdgcn_s_barrier();
      __builtin_amdgcn_sched_barrier(0);
    }
    cbB += 8192; if (cbB == 24576) cbB = 0;
    pbB += 8192; if (pbB == 24576) pbB = 0;
  }

  // hoisted epilogue: one base, compile-time offsets
  {
    float* op = outp + (long)(m0 + mw + q4 * 4) * DM + n0 + nw + l16;
#pragma unroll
    for (int mi = 0; mi < 4; ++mi)
#pragma unroll
      for (int nj = 0; nj < 4; ++nj)
#pragma unroll
        for (int r = 0; r < 4; ++r)
          op[(mi * 16 + r) * DM + nj * 16] = acc[mi][nj][r];
  }
}

// ---------------- slow GEMM (direct-global, fp32 cvt) — small-ws fallback ----
template<int MODE, bool AF32, bool WF32>
__global__ __launch_bounds__(256) void gemm_s(const void* __restrict__ Ap,
                                              const void* __restrict__ Wp,
                                              void* __restrict__ outp) {
  int wid  = (blockIdx.x * 256 + threadIdx.x) >> 6;
  int lane = threadIdx.x & 63;
  int l16  = lane & 15, q4 = lane >> 4;
  int tn = wid & 15, tm = wid >> 4;
  int m0 = tm * 32, n0 = tn * 64;

  const float*          Af = (const float*)Ap;
  const unsigned short* Ab = (const unsigned short*)Ap;
  const float*          Wf = (const float*)Wp;
  const unsigned short* Wb = (const unsigned short*)Wp;

  const f32x4 zero4 = {0.f, 0.f, 0.f, 0.f};
  f32x4 acc[2][4];
#pragma unroll
  for (int mi = 0; mi < 2; ++mi)
#pragma unroll
    for (int j = 0; j < 4; ++j) acc[mi][j] = zero4;

  int wrow[4];
#pragma unroll
  for (int j = 0; j < 4; ++j) wrow[j] = (n0 + j * 16 + l16) * DM;
  int arow[2] = {0, 0};
  long abase[2] = {0, 0};
  if (MODE != 3) {
#pragma unroll
    for (int mi = 0; mi < 2; ++mi) arow[mi] = (m0 + mi * 16 + l16) * DM;
  } else {
    int b = m0 >> 11;
#pragma unroll
    for (int mi = 0; mi < 2; ++mi) {
      int srow = (m0 & 2047) + mi * 16 + l16;
      abase[mi] = (long)b * (NH * SEQ * DKH) + (long)srow * DKH;
    }
  }

#pragma unroll 2
  for (int ks = 0; ks < 32; ++ks) {
    int ko = ks * 32 + q4 * 8;
    short8 bfrag[4];
#pragma unroll
    for (int j = 0; j < 4; ++j) {
      if constexpr (WF32) bfrag[j] = ldfrag_f32(Wf + wrow[j] + ko);
      else                bfrag[j] = ldfrag_bf(Wb + wrow[j] + ko);
    }
    short8 afrag[2];
    if constexpr (MODE != 3) {
#pragma unroll
      for (int mi = 0; mi < 2; ++mi) {
        if constexpr (AF32) afrag[mi] = ldfrag_f32(Af + arow[mi] + ko);
        else                afrag[mi] = ldfrag_bf(Ab + arow[mi] + ko);
      }
    } else {
      int h = ko >> 6, e63 = ko & 63;
#pragma unroll
      for (int mi = 0; mi < 2; ++mi)
        afrag[mi] = ldfrag_bf(Ab + abase[mi] + (long)h * (SEQ * DKH) + e63);
    }
#pragma unroll
    for (int mi = 0; mi < 2; ++mi)
#pragma unroll
      for (int j = 0; j < 4; ++j)
        acc[mi][j] = __builtin_amdgcn_mfma_f32_16x16x32_bf16(afrag[mi], bfrag[j], acc[mi][j], 0, 0, 0);
  }

#pragma unroll
  for (int mi = 0; mi < 2; ++mi) {
#pragma unroll
    for (int j = 0; j < 4; ++j) {
#pragma unroll
      for (int r = 0; r < 4; ++r) {
        float v = acc[mi][j][r];
        int m = m0 + mi * 16 + q4 * 4 + r;
        int n = n0 + j * 16 + l16;
        if constexpr (MODE == 3) {
          reinterpret_cast<float*>(outp)[(long)m * DM + n] = v;
        } else {
          int b = m >> 11, s = m & 2047;
          int h = n >> 6, d = n & 63;
          long bh = (long)(b * NH + h);
          unsigned short* o = reinterpret_cast<unsigned short*>(outp);
          if constexpr (MODE == 0)      o[(bh * SEQ + s) * DKH + d] = f2b(v * 0.125f);
          else if constexpr (MODE == 1) o[(bh * SEQ + s) * DKH + d] = f2b(v);
          else                          o[(bh * DKH + d) * SEQ + s] = f2b(v);
        }
      }
    }
  }
}

// ---------------- workgroup-tiled flash attention, 32x32 MFMA, in-reg softmax
// Swapped QK^T (mfma(K,Q)) keeps the whole softmax row in registers; exp ->
// chop-to-bf16 -> v_perm pack -> permlane32_swap feeds PV A-frags (T12).
// VALU diet: z16 const kills the per-subtile 16-mov s-init; v_perm_b32 packs
// each bf16 pair in 1 inst; float2 lsum lets the chop-sum fuse to
// v_pk_add_f32; setprio(1) wraps the MFMA clusters (T5).
__global__ __launch_bounds__(256, 4) void attn_k(const unsigned short* __restrict__ Kbuf,
                                                 const unsigned short* __restrict__ Vt,
                                                 const unsigned short* __restrict__ Qbuf,
                                                 unsigned short* __restrict__ Obuf) {
  __shared__ unsigned short Kt[2][64 * 64];    // 16 KB, double-buffered K tile
  __shared__ unsigned short Vts[2][64 * 64];   // 16 KB, double-buffered V^T tile

  int t = threadIdx.x;
  int lane = t & 63;
  int w = t >> 6;
  int l31 = lane & 31, hi = lane >> 5;
  int qb = 15 - (blockIdx.x >> 6);             // heavy blocks first
  int bh = blockIdx.x & 63;
  int q0 = qb * 128;
  int qw0 = q0 + w * 32;                       // this wave's 32 q-rows

  const unsigned short* Qh = Qbuf + (long)bh * (SEQ * DKH);
  const unsigned short* Kh = Kbuf + (long)bh * (SEQ * DKH);
  const unsigned short* Vh = Vt   + (long)bh * (DKH * SEQ);

  // Q as B-fragment for swapped QK^T: lane holds Q[q=l31][d = dt*16 + hi*8 + j]
  short8 qf[4];
#pragma unroll
  for (int dt = 0; dt < 4; ++dt)
    qf[dt] = ldfrag_bf(Qh + (long)(qw0 + l31) * DKH + dt * 16 + hi * 8);

  f32x16 z16;                                  // loop-invariant zero C operand
#pragma unroll
  for (int r = 0; r < 16; ++r) z16[r] = 0.f;

  f32x16 om[2];                                // O accum: row=q (crow), col=d
#pragma unroll
  for (int dv = 0; dv < 2; ++dv)
#pragma unroll
    for (int r = 0; r < 16; ++r) om[dv][r] = 0.f;
  f32x2 ls2 = {0.f, 0.f};                      // packed partial row-sums (q=l31)

  // K A-frag: row kr = sub*32+l31, d-chunk8 = dt*2+hi, XOR-swizzled slot
  int koff[2][4];
#pragma unroll
  for (int sub = 0; sub < 2; ++sub) {
    int kr = sub * 32 + l31;
#pragma unroll
    for (int dt = 0; dt < 4; ++dt)
      koff[sub][dt] = kr * 64 + ((dt * 2 + hi + kr + (kr >> 3)) & 7) * 8;
  }
  // V B-frag: row dr = dv*32+l31, k-chunk8 = kc*2+hi
  int voff[2][4];
#pragma unroll
  for (int dv = 0; dv < 2; ++dv) {
    int dr = dv * 32 + l31;
#pragma unroll
    for (int kc = 0; kc < 4; ++kc)
      voff[dv][kc] = dr * 64 + ((kc * 2 + hi + dr + (dr >> 3)) & 7) * 8;
  }

  // staging pointers (pre-swizzled global source, linear LDS dest)
  int rl0 = t >> 3, cp = t & 7;
  int rl1 = rl0 + 32;
  int sw0 = ((cp - rl0 - (rl0 >> 3)) & 7) * 8;
  int sw1 = ((cp - rl1 - (rl1 >> 3)) & 7) * 8;
  const unsigned short* kp0 = Kh + (long)rl0 * DKH + sw0;
  const unsigned short* kp1 = Kh + (long)rl1 * DKH + sw1;
  const unsigned short* vp0 = Vh + (long)rl0 * SEQ + sw0;
  const unsigned short* vp1 = Vh + (long)rl1 * SEQ + sw1;
  char* lK = (char*)Kt + t * 16;
  char* lV = (char*)Vts + t * 16;

  int nk = 2 * qb + 2;                         // 64-key tiles needed
  gl_lds16(kp0, lK); gl_lds16(kp1, lK + 4096);
  gl_lds16(vp0, lV); gl_lds16(vp1, lV + 4096);

  for (int it = 0; it < nk; ++it) {
    __syncthreads();                           // tile it staged
    if (it + 1 < nk) {
      kp0 += 64 * DKH; kp1 += 64 * DKH; vp0 += 64; vp1 += 64;
      int bo = ((it + 1) & 1) * 8192;
      gl_lds16(kp0, lK + bo); gl_lds16(kp1, lK + bo + 4096);
      gl_lds16(vp0, lV + bo); gl_lds16(vp1, lV + bo + 4096);
    }

    int k0 = it * 64;
    if (k0 <= qw0 + 31) {                      // wave-uniform causal activity
      const unsigned short* KT = Kt[0] + (it & 1) * 4096;
      const unsigned short* VT = Vts[0] + (it & 1) * 4096;

#pragma unroll
      for (int sub = 0; sub < 2; ++sub) {
        int ksb = k0 + sub * 32;
        if (ksb <= qw0 + 31) {                 // 32-key sub-tile active (uniform)
          // ---- swapped QK^T: S[k][q], col=q=l31, row=k=crow(r,hi)+ksb ----
          __builtin_amdgcn_s_setprio(1);
          short8 kf0 = ldfrag_bf(KT + koff[sub][0]);
          f32x16 s = __builtin_amdgcn_mfma_f32_32x32x16_bf16(kf0, qf[0], z16, 0, 0, 0);
#pragma unroll
          for (int dt = 1; dt < 4; ++dt) {
            short8 kf = ldfrag_bf(KT + koff[sub][dt]);
            s = __builtin_amdgcn_mfma_f32_32x32x16_bf16(kf, qf[dt], s, 0, 0, 0);
          }
          __builtin_amdgcn_s_setprio(0);

          // ---- exp, causal mask, chop to bf16, pack k-pairs ----
          bool needmask = (ksb + 31 > qw0);
          int qr = qw0 + l31;
          unsigned int pk[4][2];               // [m][p]: k = 8m+4hi+2p+{0,1}
#pragma unroll
          for (int r = 0; r < 16; r += 2) {
            float p0 = __expf(s[r]);
            float p1 = __expf(s[r + 1]);
            if (needmask) {
              int key = ksb + (r & 3) + 8 * (r >> 2) + 4 * hi;
              p0 = (key <= qr) ? p0 : 0.f;
              p1 = (key + 1 <= qr) ? p1 : 0.f;
            }
            unsigned int u0 = __float_as_uint(p0) & 0xffff0000u;
            unsigned int u1 = __float_as_uint(p1) & 0xffff0000u;
            f32x2 pr = {__uint_as_float(u0), __uint_as_float(u1)};
            ls2 += pr;                                           // v_pk_add_f32
            pk[r >> 2][(r >> 1) & 1] = __builtin_amdgcn_perm(u1, u0, 0x07060302u);
          }

          // ---- redistribute into PV A-frags: one swap fills two words ----
#pragma unroll
          for (int c = 0; c < 2; ++c) {
            u32x2 r0 = __builtin_amdgcn_permlane32_swap(pk[2 * c][0], pk[2 * c + 1][0], false, false);
            u32x2 r1 = __builtin_amdgcn_permlane32_swap(pk[2 * c][1], pk[2 * c + 1][1], false, false);
            u32x4 pw;
            pw.x = r0.x; pw.y = r1.x; pw.z = r0.y; pw.w = r1.y;
            short8 pa = __builtin_bit_cast(short8, pw);  // P[q=l31][k'=8hi+j]
            int kc = sub * 2 + c;
            __builtin_amdgcn_s_setprio(1);
#pragma unroll
            for (int dv = 0; dv < 2; ++dv) {
              short8 vf = ldfrag_bf(VT + voff[dv][kc]);
              om[dv] = __builtin_amdgcn_mfma_f32_32x32x16_bf16(pa, vf, om[dv], 0, 0, 0);
            }
            __builtin_amdgcn_s_setprio(0);
          }
        }
      }
    }
  }

  // ---- normalize: partner-sum lsum (lane l <-> l+32 share q=l31) ----
  float lsum = ls2[0] + ls2[1];
  u32x2 lz = __builtin_amdgcn_permlane32_swap(__float_as_uint(lsum), __float_as_uint(lsum),
                                              false, false);
  float inv = 1.f / (__uint_as_float(lz.x) + __uint_as_float(lz.y));  // for q=l31

  long obase = (long)bh * (SEQ * DKH);
#pragma unroll
  for (int r = 0; r < 16; ++r) {
    int qrow = (r & 3) + 8 * (r >> 2) + 4 * hi;   // om row -> q
    float invq = __shfl(inv, qrow);               // inv for that q lives at lane qrow
    long rowb = obase + (long)(qw0 + qrow) * DKH + l31;
    Obuf[rowb]      = f2b(om[0][r] * invq);
    Obuf[rowb + 32] = f2b(om[1][r] * invq);
  }
}

extern "C" void kernel_launch(void* const* d_in, const int* in_sizes, int n_in,
                              void* d_out, int out_size, void* d_ws, size_t ws_size,
                              hipStream_t stream) {
  const float* x  = (const float*)d_in[0];
  const float* wq = (const float*)d_in[1];
  const float* wk = (const float*)d_in[2];
  const float* wv = (const float*)d_in[3];
  const float* wo = (const float*)d_in[4];

  // Q/K bf16 staged in d_out (exactly 16M ushorts); final GEMM overwrites with fp32.
  unsigned short* Qb = (unsigned short*)d_out;
  unsigned short* Kb = Qb + 8388608;

  if (ws_size >= 41943040ull) {
    // ---- fast path (>=40 MiB ws): xb 16 MiB | weights 8 MiB | Vt 16 MiB ----
    unsigned short* xb  = (unsigned short*)d_ws;   // becomes O after projections
    unsigned short* wqb = xb + 8388608;
    unsigned short* wkb = wqb + 1048576;
    unsigned short* wvb = wkb + 1048576;
    unsigned short* wob = wvb + 1048576;
    unsigned short* Vt  = wob + 1048576;           // [B,H,dk,S]
    unsigned short* Ob  = xb;

    cast_all<<<12288, 256, 0, stream>>>(x, wq, wk, wv, wo, xb, wqb, wkb, wvb, wob);

    gemm_qkv<<<512, 256, 0, stream>>>(xb, wqb, wkb, wvb, Qb, Kb, Vt);
    attn_k<<<1024, 256, 0, stream>>>(Kb, Vt, Qb, Ob);
    gemm_o<<<512, 256, 0, stream>>>(Ob, wob, (float*)d_out);
  } else if (ws_size >= 33554432ull) {
    // ---- minimal path (32 MiB ws): fp32 direct gemms, fast attention ----
    unsigned short* Vt = (unsigned short*)d_ws;   // 8M els [B,H,dk,S]
    unsigned short* Ob = Vt + 8388608;            // 8M els [B,H,S,dk]

    gemm_s<0, true, true><<<1024, 256, 0, stream>>>(x, wq, Qb);
    gemm_s<1, true, true><<<1024, 256, 0, stream>>>(x, wk, Kb);
    gemm_s<2, true, true><<<1024, 256, 0, stream>>>(x, wv, Vt);
    attn_k<<<1024, 256, 0, stream>>>(Kb, Vt, Qb, Ob);
    gemm_s<3, false, true><<<1024, 256, 0, stream>>>(Ob, wo, d_out);
  } else {
    zero_f32<<<8192, 256, 0, stream>>>((float*)d_out, 2097152);
  }
}